// Round 4
// baseline (1665.743 us; speedup 1.0000x reference)
//
#include <hip/hip_runtime.h>
#include <hip/hip_bf16.h>

typedef __bf16 bf16_t;
typedef __bf16 bf16x8 __attribute__((ext_vector_type(8)));
typedef float  f32x4  __attribute__((ext_vector_type(4)));

static constexpr int N_NODES = 100000;
static constexpr int N_EDGES = 300000;
static constexpr int N_GRAPH = 4096;
static constexpr int H  = 256;
static constexpr int ND = 64;
static constexpr int ED = 16;
static constexpr int ZIC = 128;
static constexpr int NE = 8;

__device__ __forceinline__ int clampi(int v, int lo, int hi) {
  return v < lo ? lo : (v > hi ? hi : v);
}

// ---------------- graph segment starts (batch is sorted) ----------------
__global__ void compute_starts_kernel(const int* __restrict__ batch,
                                      int* __restrict__ starts, int N, int G) {
  int i = blockIdx.x * blockDim.x + threadIdx.x;
  if (i >= N) return;
  int b = clampi(batch[i], 0, G - 1);
  if (i == 0) {
    for (int g = 0; g <= b; ++g) starts[g] = 0;
  } else {
    int p = clampi(batch[i - 1], 0, G - 1);
    for (int g = p + 1; g <= b; ++g) starts[g] = i;
  }
  if (i == N - 1) {
    for (int g = b + 1; g <= G; ++g) starts[g] = N;
  }
}

// ---------------- CSR build ----------------
__global__ void zero2_kernel(int* __restrict__ a, int* __restrict__ b, int N) {
  int i = blockIdx.x * blockDim.x + threadIdx.x;
  if (i < N) { a[i] = 0; b[i] = 0; }
}

__global__ void count_deg_kernel(const int* __restrict__ dst, int* __restrict__ counts, int E, int N) {
  int e = blockIdx.x * blockDim.x + threadIdx.x;
  if (e < E) atomicAdd(&counts[clampi(dst[e], 0, N - 1)], 1);
}

// single-block chunked inclusive scan -> exclusive offsets (serial carry)
__global__ __launch_bounds__(1024) void scan_kernel(const int* __restrict__ counts,
                                                    int* __restrict__ offs, int N) {
  __shared__ int tmp[1024];
  __shared__ int carry_s;
  if (threadIdx.x == 0) { carry_s = 0; offs[0] = 0; }
  __syncthreads();
  for (int base = 0; base < N; base += 1024) {
    int i = base + threadIdx.x;
    int v = (i < N) ? counts[i] : 0;
    tmp[threadIdx.x] = v;
    __syncthreads();
    for (int d = 1; d < 1024; d <<= 1) {
      int t = (threadIdx.x >= d) ? tmp[threadIdx.x - d] : 0;
      __syncthreads();
      tmp[threadIdx.x] += t;
      __syncthreads();
    }
    int carry = carry_s;
    if (i < N) offs[i + 1] = carry + tmp[threadIdx.x];
    int total = tmp[1023];
    __syncthreads();
    if (threadIdx.x == 0) carry_s = carry + total;
    __syncthreads();
  }
}

__global__ void fill_perm_kernel(const int* __restrict__ dst, const int* __restrict__ offs,
                                 int* __restrict__ cursor, int* __restrict__ perm, int E, int N) {
  int e = blockIdx.x * blockDim.x + threadIdx.x;
  if (e >= E) return;
  int d = clampi(dst[e], 0, N - 1);
  int pos = offs[d] + atomicAdd(&cursor[d], 1);
  if ((unsigned)pos < (unsigned)E) perm[pos] = e;
}

// -------- fp32 transpose + bf16 cast: W[K x Nc] -> Wt[Nc x K] (bf16) ------
__global__ void transpose_kernel(const float* __restrict__ W,
                                 bf16_t* __restrict__ Wt, int K, int Nc) {
  __shared__ float tile[32][33];
  int n0 = blockIdx.x * 32, k0 = blockIdx.y * 32;
  int tx = threadIdx.x, ty = threadIdx.y;
  for (int i = ty; i < 32; i += 8)
    tile[i][tx] = W[(size_t)(k0 + i) * Nc + n0 + tx];
  __syncthreads();
  for (int i = ty; i < 32; i += 8)
    Wt[(size_t)(n0 + i) * K + k0 + tx] = (bf16_t)tile[tx][i];
}

// ---- staging loaders: 8 contiguous elements -> 8 bf16 (16B) in LDS ----
__device__ __forceinline__ void load8_to_lds(const bf16_t* p, bool valid, uint4* dst) {
  uint4 v = make_uint4(0u, 0u, 0u, 0u);
  if (valid) v = *(const uint4*)p;
  *dst = v;
}
__device__ __forceinline__ void load8_to_lds(const float* p, bool valid, uint4* dst) {
  float4 f0 = make_float4(0.f, 0.f, 0.f, 0.f), f1 = f0;
  if (valid) { f0 = *(const float4*)p; f1 = *(const float4*)(p + 4); }
  union { bf16_t b[8]; uint4 u; } pk;
  pk.b[0] = (bf16_t)f0.x; pk.b[1] = (bf16_t)f0.y;
  pk.b[2] = (bf16_t)f0.z; pk.b[3] = (bf16_t)f0.w;
  pk.b[4] = (bf16_t)f1.x; pk.b[5] = (bf16_t)f1.y;
  pk.b[6] = (bf16_t)f1.z; pk.b[7] = (bf16_t)f1.w;
  *dst = pk.u;
}

// ---------------- MFMA GEMM: Out[M x Nc] = act(U[M x K] @ W + bias) ------
// U row-major [M x K] (fp32 or bf16); Wt bf16 [Nc x K]. BM=BN=64, BK=32,
// 4 waves 2x2. Frags (guide §3, m89/m91/m92): A: m=lane&15,k=quad*8+j;
// B: n=lane&15,k=quad*8+j; D: col=lane&15, row=quad*4+r.
template<int K, bool RELU, typename TIN>
__global__ __launch_bounds__(256) void gemm_kernel(
    const TIN* __restrict__ U, const bf16_t* __restrict__ Wt,
    const float* __restrict__ bias, bf16_t* __restrict__ Out, int M, int Nc) {
  constexpr int LDT = 40;  // 80B rows: 16B-aligned, 2-way banks (free)
  __shared__ bf16_t Ut[64 * LDT];
  __shared__ bf16_t Wl[64 * LDT];
  const int m0 = blockIdx.x * 64;
  const int n0 = blockIdx.y * 64;
  const int t = threadIdx.x;
  const int lane = t & 63;
  const int wave = t >> 6;
  const int wm = (wave >> 1) * 32;
  const int wn = (wave & 1) * 32;
  const int srow = t >> 2;
  const int sk = (t & 3) * 8;
  const int lr = lane & 15;
  const int lq = lane >> 4;
  f32x4 acc[2][2] = {};

  for (int k0 = 0; k0 < K; k0 += 32) {
    load8_to_lds(U + (size_t)(m0 + srow) * K + k0 + sk, m0 + srow < M,
                 (uint4*)&Ut[srow * LDT + sk]);
    load8_to_lds(Wt + (size_t)(n0 + srow) * K + k0 + sk, true,
                 (uint4*)&Wl[srow * LDT + sk]);
    __syncthreads();
    bf16x8 a[2], b[2];
#pragma unroll
    for (int mt = 0; mt < 2; ++mt)
      a[mt] = *(const bf16x8*)(&Ut[(wm + mt * 16 + lr) * LDT + lq * 8]);
#pragma unroll
    for (int nt = 0; nt < 2; ++nt)
      b[nt] = *(const bf16x8*)(&Wl[(wn + nt * 16 + lr) * LDT + lq * 8]);
#pragma unroll
    for (int mt = 0; mt < 2; ++mt)
#pragma unroll
      for (int nt = 0; nt < 2; ++nt)
        acc[mt][nt] = __builtin_amdgcn_mfma_f32_16x16x32_bf16(
            a[mt], b[nt], acc[mt][nt], 0, 0, 0);
    __syncthreads();
  }

#pragma unroll
  for (int mt = 0; mt < 2; ++mt)
#pragma unroll
    for (int nt = 0; nt < 2; ++nt) {
      int col = n0 + wn + nt * 16 + lr;
      float bcol = bias[col];
#pragma unroll
      for (int r = 0; r < 4; ++r) {
        int row = m0 + wm + mt * 16 + lq * 4 + r;
        if (row < M) {
          float vv = acc[mt][nt][r] + bcol;
          if (RELU) vv = vv > 0.f ? vv : 0.f;
          Out[(size_t)row * Nc + col] = (bf16_t)vv;
        }
      }
    }
}

// ---------------- GINE gather: u = (1+eps)*h + sum_in relu(h_src+lin(e)) --
__global__ __launch_bounds__(256) void gine_gather_kernel(
    const bf16_t* __restrict__ h, const float* __restrict__ eattr,
    const int* __restrict__ src, const int* __restrict__ perm,
    const int* __restrict__ offs, const float* __restrict__ eW,
    const float* __restrict__ eb, const float* __restrict__ eps_p,
    bf16_t* __restrict__ u) {
  const int n = blockIdx.x, c = threadIdx.x;
  __shared__ float sea[32 * ED];
  __shared__ int ssrc[32];
  float w[ED];
#pragma unroll
  for (int k = 0; k < ED; ++k) w[k] = eW[k * H + c];
  const float ebc = eb[c];
  int s0 = offs[n], s1 = offs[n + 1];
  s0 = clampi(s0, 0, N_EDGES);
  s1 = clampi(s1, s0, N_EDGES);
  float acc = 0.f;
  for (int base = s0; base < s1; base += 32) {
    int rem = s1 - base;
    const int cnt = rem < 32 ? rem : 32;
    if (c < cnt) {
      int pe = perm[base + c];
      pe = ((unsigned)pe < (unsigned)N_EDGES) ? pe : 0;
      int sid = src[pe];
      ssrc[c] = ((unsigned)sid < (unsigned)N_NODES) ? sid : 0;
    }
    for (int t2 = c; t2 < cnt * ED; t2 += 256) {
      int j = t2 >> 4, k = t2 & 15;
      int pe = perm[base + j];
      pe = ((unsigned)pe < (unsigned)N_EDGES) ? pe : 0;
      sea[j * ED + k] = eattr[(size_t)pe * ED + k];
    }
    __syncthreads();
    for (int j = 0; j < cnt; ++j) {
      float lin = ebc;
#pragma unroll
      for (int k = 0; k < ED; ++k) lin += sea[j * ED + k] * w[k];
      float m = (float)h[(size_t)ssrc[j] * H + c] + lin;
      acc += fmaxf(m, 0.f);
    }
    __syncthreads();
  }
  const float sc = 1.0f + eps_p[0];
  u[(size_t)n * H + c] = (bf16_t)(sc * (float)h[(size_t)n * H + c] + acc);
}

// ---------------- GraphNorm (+relu) 2-pass, one block/graph ----------------
__global__ void graphnorm_kernel(const bf16_t* __restrict__ v, bf16_t* __restrict__ hout,
                                 const int* __restrict__ starts,
                                 const float* __restrict__ w, const float* __restrict__ b,
                                 const float* __restrict__ ms) {
  const int g = blockIdx.x, c = threadIdx.x;
  int s = starts[g], e = starts[g + 1];
  s = clampi(s, 0, N_NODES);
  e = clampi(e, s, N_NODES);
  const float cnt = (float)((e - s) > 1 ? (e - s) : 1);
  float sx = 0.f, sxx = 0.f;
  for (int i = s; i < e; ++i) {
    float xv = (float)v[(size_t)i * H + c];
    sx += xv; sxx += xv * xv;
  }
  const float mean = sx / cnt;
  const float sub = ms[c] * mean;
  float var = sxx / cnt - 2.f * sub * mean + sub * sub;
  var = fmaxf(var, 0.f);
  const float inv = rsqrtf(var + 1e-5f) * w[c];
  const float bb = b[c];
  for (int i = s; i < e; ++i) {
    float o = ((float)v[(size_t)i * H + c] - sub) * inv + bb;
    hout[(size_t)i * H + c] = (bf16_t)(o > 0.f ? o : 0.f);
  }
}

// ---------------- global mean pool -> fp32 (direct to d_out) --------------
__global__ void pool_kernel(const bf16_t* __restrict__ h, const int* __restrict__ starts,
                            float* __restrict__ hg) {
  const int g = blockIdx.x, c = threadIdx.x;
  int s = starts[g], e = starts[g + 1];
  s = clampi(s, 0, N_NODES);
  e = clampi(e, s, N_NODES);
  const float cnt = (float)((e - s) > 1 ? (e - s) : 1);
  float sum = 0.f;
  for (int i = s; i < e; ++i) sum += (float)h[(size_t)i * H + c];
  hg[(size_t)g * H + c] = sum / cnt;
}

// ---------------- small dense: Out[M x Nc] = act(In@W + b), all fp32 ------
__global__ void small_gemm_kernel(const float* __restrict__ In, const float* __restrict__ W,
                                  const float* __restrict__ bias, float* __restrict__ Out,
                                  int M, int K, int Nc, int relu) {
  int idx = blockIdx.x * blockDim.x + threadIdx.x;
  if (idx >= M * Nc) return;
  int r = idx / Nc, n = idx - r * Nc;
  float acc = bias[n];
  const float* in = In + (size_t)r * K;
  for (int k = 0; k < K; ++k) acc += in[k] * W[(size_t)k * Nc + n];
  if (relu && acc < 0.f) acc = 0.f;
  Out[idx] = acc;
}

extern "C" void kernel_launch(void* const* d_in, const int* in_sizes, int n_in,
                              void* d_out, int out_size, void* d_ws, size_t ws_size,
                              hipStream_t stream) {
  (void)in_sizes; (void)n_in; (void)out_size; (void)ws_size;
  const float* x        = (const float*)d_in[0];
  const int*   eidx     = (const int*)d_in[1];
  const float* eattr    = (const float*)d_in[2];
  const int*   batch    = (const int*)d_in[3];
  const float* node_W   = (const float*)d_in[4];
  const float* node_b   = (const float*)d_in[5];
  const float* conv_eps = (const float*)d_in[6];
  const float* edge_W   = (const float*)d_in[7];
  const float* edge_b   = (const float*)d_in[8];
  const float* mlp_W1   = (const float*)d_in[9];
  const float* mlp_b1   = (const float*)d_in[10];
  const float* mlp_W2   = (const float*)d_in[11];
  const float* mlp_b2   = (const float*)d_in[12];
  const float* gn_w     = (const float*)d_in[13];
  const float* gn_b     = (const float*)d_in[14];
  const float* gn_ms    = (const float*)d_in[15];
  const float* finv_W1  = (const float*)d_in[16];
  const float* finv_b1  = (const float*)d_in[17];
  const float* finv_W2  = (const float*)d_in[18];
  const float* finv_b2  = (const float*)d_in[19];
  const float* fspu_W1  = (const float*)d_in[20];
  const float* fspu_b1  = (const float*)d_in[21];
  const float* fspu_W2  = (const float*)d_in[22];
  const float* fspu_b2  = (const float*)d_in[23];
  const float* pred_W1  = (const float*)d_in[24];
  const float* pred_b1  = (const float*)d_in[25];
  const float* pred_W2  = (const float*)d_in[26];
  const float* pred_b2  = (const float*)d_in[27];
  const float* adv_W1   = (const float*)d_in[28];
  const float* adv_b1   = (const float*)d_in[29];
  const float* adv_W2   = (const float*)d_in[30];
  const float* adv_b2   = (const float*)d_in[31];
  float* out = (float*)d_out;

  // d_out slices (fp32, written in place; hg/zi reused as head inputs)
  float* out_hg = out;                                  // [G,H]
  float* out_zi = out + (size_t)N_GRAPH * H;            // [G,ZI]
  float* out_zs = out_zi + (size_t)N_GRAPH * ZIC;       // [G,ZS]
  float* out_yh = out_zs + (size_t)N_GRAPH * ZIC;       // [G]
  float* out_ev = out_yh + N_GRAPH;                     // [G,NE]

  // workspace carve-up (~110 MiB total)
  char* wp = (char*)d_ws;
  auto alloc = [&](size_t bytes) { char* p = wp; wp += (bytes + 255) & ~(size_t)255; return p; };
  bf16_t* A      = (bf16_t*)alloc((size_t)N_NODES * H * 2);   // h / t
  bf16_t* B      = (bf16_t*)alloc((size_t)N_NODES * H * 2);   // u / v
  bf16_t* Wt     = (bf16_t*)alloc((size_t)(H * ND + 6 * H * H) * 2);
  int*    starts = (int*)alloc((size_t)(N_GRAPH + 1) * 4);
  int*    counts = (int*)alloc((size_t)N_NODES * 4);
  int*    cursor = (int*)alloc((size_t)N_NODES * 4);
  int*    offs   = (int*)alloc((size_t)(N_NODES + 1) * 4);
  int*    perm   = (int*)alloc((size_t)N_EDGES * 4);
  float*  tmp1   = (float*)alloc((size_t)N_GRAPH * ZIC * 4);
  float*  tmp2   = (float*)alloc((size_t)N_GRAPH * ZIC * 4);

  const int* srcp = eidx;
  const int* dstp = eidx + N_EDGES;

  compute_starts_kernel<<<(N_NODES + 255) / 256, 256, 0, stream>>>(batch, starts, N_NODES, N_GRAPH);

  // CSR build (edges grouped by dst)
  zero2_kernel<<<(N_NODES + 255) / 256, 256, 0, stream>>>(counts, cursor, N_NODES);
  count_deg_kernel<<<(N_EDGES + 255) / 256, 256, 0, stream>>>(dstp, counts, N_EDGES, N_NODES);
  scan_kernel<<<1, 1024, 0, stream>>>(counts, offs, N_NODES);
  fill_perm_kernel<<<(N_EDGES + 255) / 256, 256, 0, stream>>>(dstp, offs, cursor, perm, N_EDGES, N_NODES);

  // transpose (+bf16-cast) all MFMA weights upfront
  bf16_t* WtN = Wt;
  auto Wt1l = [&](int l) { return Wt + H * ND + (size_t)(2 * l) * H * H; };
  auto Wt2l = [&](int l) { return Wt + H * ND + (size_t)(2 * l + 1) * H * H; };
  transpose_kernel<<<dim3(H / 32, ND / 32), dim3(32, 8), 0, stream>>>(node_W, WtN, ND, H);
  for (int l = 0; l < 3; ++l) {
    transpose_kernel<<<dim3(H / 32, H / 32), dim3(32, 8), 0, stream>>>(mlp_W1 + (size_t)l * H * H, Wt1l(l), H, H);
    transpose_kernel<<<dim3(H / 32, H / 32), dim3(32, 8), 0, stream>>>(mlp_W2 + (size_t)l * H * H, Wt2l(l), H, H);
  }

  dim3 ggrid((N_NODES + 63) / 64, H / 64);
  // h = x @ node_W + node_b  (fp32 x converted in staging) -> A (bf16)
  gemm_kernel<ND, false><<<ggrid, 256, 0, stream>>>(x, WtN, node_b, A, N_NODES, H);

  for (int l = 0; l < 3; ++l) {
    gine_gather_kernel<<<N_NODES, H, 0, stream>>>(A, eattr, srcp, perm, offs,
                                                  edge_W + (size_t)l * ED * H,
                                                  edge_b + l * H, conv_eps + l, B);
    gemm_kernel<H, true ><<<ggrid, 256, 0, stream>>>(B, Wt1l(l), mlp_b1 + l * H, A, N_NODES, H);
    gemm_kernel<H, false><<<ggrid, 256, 0, stream>>>(A, Wt2l(l), mlp_b2 + l * H, B, N_NODES, H);
    graphnorm_kernel<<<N_GRAPH, H, 0, stream>>>(B, A, starts, gn_w + l * H, gn_b + l * H, gn_ms + l * H);
  }

  pool_kernel<<<N_GRAPH, H, 0, stream>>>(A, starts, out_hg);

  auto sg = [&](const float* In, const float* W, const float* b, float* Out,
                int M, int K, int Nc, int relu) {
    small_gemm_kernel<<<(M * Nc + 255) / 256, 256, 0, stream>>>(In, W, b, Out, M, K, Nc, relu);
  };
  sg(out_hg, finv_W1, finv_b1, tmp1,   N_GRAPH, H,   ZIC, 1);
  sg(tmp1,   finv_W2, finv_b2, out_zi, N_GRAPH, ZIC, ZIC, 0);
  sg(out_hg, fspu_W1, fspu_b1, tmp2,   N_GRAPH, H,   ZIC, 1);
  sg(tmp2,   fspu_W2, fspu_b2, out_zs, N_GRAPH, ZIC, ZIC, 0);
  sg(out_zi, pred_W1, pred_b1, tmp1,   N_GRAPH, ZIC, ZIC, 1);
  sg(tmp1,   pred_W2, pred_b2, out_yh, N_GRAPH, ZIC, 1,   0);
  sg(out_zi, adv_W1,  adv_b1,  tmp2,   N_GRAPH, ZIC, ZIC, 1);
  sg(tmp2,   adv_W2,  adv_b2,  out_ev, N_GRAPH, ZIC, NE,  0);
}

// Round 5
// 1463.782 us; speedup vs baseline: 1.1380x; 1.1380x over previous
//
#include <hip/hip_runtime.h>
#include <hip/hip_bf16.h>

typedef __bf16 bf16_t;
typedef __bf16 bf16x8 __attribute__((ext_vector_type(8)));
typedef float  f32x4  __attribute__((ext_vector_type(4)));

static constexpr int N_NODES = 100000;
static constexpr int N_EDGES = 300000;
static constexpr int N_GRAPH = 4096;
static constexpr int H  = 256;
static constexpr int ND = 64;
static constexpr int ED = 16;
static constexpr int ZIC = 128;
static constexpr int NE = 8;
static constexpr int SCAN_B = 1024;

__device__ __forceinline__ int clampi(int v, int lo, int hi) {
  return v < lo ? lo : (v > hi ? hi : v);
}

// ---------------- graph segment starts (batch is sorted) ----------------
__global__ void compute_starts_kernel(const int* __restrict__ batch,
                                      int* __restrict__ starts, int N, int G) {
  int i = blockIdx.x * blockDim.x + threadIdx.x;
  if (i >= N) return;
  int b = clampi(batch[i], 0, G - 1);
  if (i == 0) {
    for (int g = 0; g <= b; ++g) starts[g] = 0;
  } else {
    int p = clampi(batch[i - 1], 0, G - 1);
    for (int g = p + 1; g <= b; ++g) starts[g] = i;
  }
  if (i == N - 1) {
    for (int g = b + 1; g <= G; ++g) starts[g] = N;
  }
}

// ---------------- CSR build ----------------
__global__ void zero2_kernel(int* __restrict__ a, int* __restrict__ b, int N) {
  int i = blockIdx.x * blockDim.x + threadIdx.x;
  if (i < N) { a[i] = 0; b[i] = 0; }
}

__global__ void count_deg_kernel(const int* __restrict__ dst, int* __restrict__ counts, int E, int N) {
  int e = blockIdx.x * blockDim.x + threadIdx.x;
  if (e < E) atomicAdd(&counts[clampi(dst[e], 0, N - 1)], 1);
}

// multi-block scan: per-block inclusive scan + block sums
__global__ __launch_bounds__(SCAN_B) void scan1_kernel(const int* __restrict__ counts,
                                                       int* __restrict__ offs,
                                                       int* __restrict__ bsum, int N) {
  __shared__ int tmp[SCAN_B];
  int i = blockIdx.x * SCAN_B + threadIdx.x;
  int v = (i < N) ? counts[i] : 0;
  tmp[threadIdx.x] = v;
  __syncthreads();
  for (int d = 1; d < SCAN_B; d <<= 1) {
    int t = (threadIdx.x >= d) ? tmp[threadIdx.x - d] : 0;
    __syncthreads();
    tmp[threadIdx.x] += t;
    __syncthreads();
  }
  if (i < N) offs[i + 1] = tmp[threadIdx.x];
  if (threadIdx.x == SCAN_B - 1) bsum[blockIdx.x] = tmp[SCAN_B - 1];
  if (i == 0) offs[0] = 0;
}

__global__ void scan2_kernel(int* __restrict__ bsum, int nblk) {
  if (blockIdx.x == 0 && threadIdx.x == 0) {
    int run = 0;
    for (int b = 0; b < nblk; ++b) { int v = bsum[b]; bsum[b] = run; run += v; }
  }
}

__global__ __launch_bounds__(SCAN_B) void scan3_kernel(int* __restrict__ offs,
                                                       const int* __restrict__ bsum, int N) {
  int i = blockIdx.x * SCAN_B + threadIdx.x;
  if (i < N) offs[i + 1] += bsum[blockIdx.x];
}

__global__ void fill_perm_kernel(const int* __restrict__ dst, const int* __restrict__ offs,
                                 int* __restrict__ cursor, int* __restrict__ perm, int E, int N) {
  int e = blockIdx.x * blockDim.x + threadIdx.x;
  if (e >= E) return;
  int d = clampi(dst[e], 0, N - 1);
  int pos = offs[d] + atomicAdd(&cursor[d], 1);
  if ((unsigned)pos < (unsigned)E) perm[pos] = e;
}

// src_sorted[pos] = src[perm[pos]]  (layer-invariant, built once)
__global__ void sort_src_kernel(const int* __restrict__ perm, const int* __restrict__ src,
                                int* __restrict__ src_sorted, int E) {
  int p = blockIdx.x * blockDim.x + threadIdx.x;
  if (p >= E) return;
  int e = perm[p];
  e = ((unsigned)e < (unsigned)E) ? e : 0;
  int s = src[e];
  src_sorted[p] = ((unsigned)s < (unsigned)N_NODES) ? s : 0;
}

// -------- fp32 transpose + bf16 cast: W[K x Nc] -> Wt[Nc x K] (bf16) ------
__global__ void transpose_kernel(const float* __restrict__ W,
                                 bf16_t* __restrict__ Wt, int K, int Nc) {
  __shared__ float tile[32][33];
  int n0 = blockIdx.x * 32, k0 = blockIdx.y * 32;
  int tx = threadIdx.x, ty = threadIdx.y;
  for (int i = ty; i < 32; i += 8)
    tile[i][tx] = W[(size_t)(k0 + i) * Nc + n0 + tx];
  __syncthreads();
  for (int i = ty; i < 32; i += 8)
    Wt[(size_t)(n0 + i) * K + k0 + tx] = (bf16_t)tile[tx][i];
}

// ---- staging loaders: 8 contiguous elements -> 8 bf16 (16B) in LDS ----
__device__ __forceinline__ void load8_to_lds(const bf16_t* p, bool valid, uint4* dst) {
  uint4 v = make_uint4(0u, 0u, 0u, 0u);
  if (valid) v = *(const uint4*)p;
  *dst = v;
}
__device__ __forceinline__ void load8_to_lds(const float* p, bool valid, uint4* dst) {
  float4 f0 = make_float4(0.f, 0.f, 0.f, 0.f), f1 = f0;
  if (valid) { f0 = *(const float4*)p; f1 = *(const float4*)(p + 4); }
  union { bf16_t b[8]; uint4 u; } pk;
  pk.b[0] = (bf16_t)f0.x; pk.b[1] = (bf16_t)f0.y;
  pk.b[2] = (bf16_t)f0.z; pk.b[3] = (bf16_t)f0.w;
  pk.b[4] = (bf16_t)f1.x; pk.b[5] = (bf16_t)f1.y;
  pk.b[6] = (bf16_t)f1.z; pk.b[7] = (bf16_t)f1.w;
  *dst = pk.u;
}

// ---------------- MFMA GEMM: Out[M x Nc] = act(U[M x K] @ W + bias) ------
// U row-major [M x K] (fp32 or bf16); Wt bf16 [Nc x K]. BM=BN=64, BK=64,
// 4 waves 2x2. Frags (guide §3, m89/m91/m92): A: m=lane&15,k=quad*8+j;
// B: n=lane&15,k=quad*8+j; D: col=lane&15, row=quad*4+r.
template<int K, bool RELU, typename TIN>
__global__ __launch_bounds__(256) void gemm_kernel(
    const TIN* __restrict__ U, const bf16_t* __restrict__ Wt,
    const float* __restrict__ bias, bf16_t* __restrict__ Out, int M, int Nc) {
  constexpr int LDT = 72;  // 144B rows: 16B-aligned; ds_read 2-way banks (free)
  __shared__ bf16_t Ut[64 * LDT];
  __shared__ bf16_t Wl[64 * LDT];
  const int m0 = blockIdx.x * 64;
  const int n0 = blockIdx.y * 64;
  const int t = threadIdx.x;
  const int lane = t & 63;
  const int wave = t >> 6;
  const int wm = (wave >> 1) * 32;
  const int wn = (wave & 1) * 32;
  const int srow = t >> 2;
  const int sk = (t & 3) * 8;
  const int lr = lane & 15;
  const int lq = lane >> 4;
  const bool arow_ok = (m0 + srow) < M;
  f32x4 acc[2][2] = {};

  for (int k0 = 0; k0 < K; k0 += 64) {
    const TIN* up = U + (size_t)(m0 + srow) * K + k0 + sk;
    const bf16_t* wp = Wt + (size_t)(n0 + srow) * K + k0 + sk;
    load8_to_lds(up,      arow_ok, (uint4*)&Ut[srow * LDT + sk]);
    load8_to_lds(up + 32, arow_ok, (uint4*)&Ut[srow * LDT + sk + 32]);
    load8_to_lds(wp,      true,    (uint4*)&Wl[srow * LDT + sk]);
    load8_to_lds(wp + 32, true,    (uint4*)&Wl[srow * LDT + sk + 32]);
    __syncthreads();
#pragma unroll
    for (int s = 0; s < 2; ++s) {
      bf16x8 a[2], b[2];
#pragma unroll
      for (int mt = 0; mt < 2; ++mt)
        a[mt] = *(const bf16x8*)(&Ut[(wm + mt * 16 + lr) * LDT + s * 32 + lq * 8]);
#pragma unroll
      for (int nt = 0; nt < 2; ++nt)
        b[nt] = *(const bf16x8*)(&Wl[(wn + nt * 16 + lr) * LDT + s * 32 + lq * 8]);
#pragma unroll
      for (int mt = 0; mt < 2; ++mt)
#pragma unroll
        for (int nt = 0; nt < 2; ++nt)
          acc[mt][nt] = __builtin_amdgcn_mfma_f32_16x16x32_bf16(
              a[mt], b[nt], acc[mt][nt], 0, 0, 0);
    }
    __syncthreads();
  }

#pragma unroll
  for (int mt = 0; mt < 2; ++mt)
#pragma unroll
    for (int nt = 0; nt < 2; ++nt) {
      int col = n0 + wn + nt * 16 + lr;
      float bcol = bias[col];
#pragma unroll
      for (int r = 0; r < 4; ++r) {
        int row = m0 + wm + mt * 16 + lq * 4 + r;
        if (row < M) {
          float vv = acc[mt][nt][r] + bcol;
          if (RELU) vv = vv > 0.f ? vv : 0.f;
          Out[(size_t)row * Nc + col] = (bf16_t)vv;
        }
      }
    }
}

// ---------------- GINE gather: u = (1+eps)*h + sum_in relu(h_src+lin(e)) --
__global__ __launch_bounds__(256) void gine_gather_kernel(
    const bf16_t* __restrict__ h, const float* __restrict__ eattr,
    const int* __restrict__ src_sorted, const int* __restrict__ perm,
    const int* __restrict__ offs, const float* __restrict__ eW,
    const float* __restrict__ eb, const float* __restrict__ eps_p,
    bf16_t* __restrict__ u) {
  const int n = blockIdx.x, c = threadIdx.x;
  __shared__ float sea[32 * ED];
  __shared__ int ssrc[32];
  __shared__ int sperm[32];
  float w[ED];
#pragma unroll
  for (int k = 0; k < ED; ++k) w[k] = eW[k * H + c];
  const float ebc = eb[c];
  int s0 = offs[n], s1 = offs[n + 1];
  s0 = clampi(s0, 0, N_EDGES);
  s1 = clampi(s1, s0, N_EDGES);
  float acc = 0.f;
  for (int base = s0; base < s1; base += 32) {
    int rem = s1 - base;
    const int cnt = rem < 32 ? rem : 32;
    if (c < cnt) {
      ssrc[c] = src_sorted[base + c];
      int pe = perm[base + c];
      sperm[c] = ((unsigned)pe < (unsigned)N_EDGES) ? pe : 0;
    }
    __syncthreads();
    for (int t2 = c; t2 < cnt * ED; t2 += 256) {
      int j = t2 >> 4, k = t2 & 15;
      sea[t2] = eattr[(size_t)sperm[j] * ED + k];
    }
    __syncthreads();
    for (int j = 0; j < cnt; ++j) {
      float lin = ebc;
#pragma unroll
      for (int k = 0; k < ED; ++k) lin += sea[j * ED + k] * w[k];
      float m = (float)h[(size_t)ssrc[j] * H + c] + lin;
      acc += fmaxf(m, 0.f);
    }
    __syncthreads();
  }
  const float sc = 1.0f + eps_p[0];
  u[(size_t)n * H + c] = (bf16_t)(sc * (float)h[(size_t)n * H + c] + acc);
}

// ---------------- GraphNorm (+relu) 2-pass, one block/graph ----------------
__global__ void graphnorm_kernel(const bf16_t* __restrict__ v, bf16_t* __restrict__ hout,
                                 const int* __restrict__ starts,
                                 const float* __restrict__ w, const float* __restrict__ b,
                                 const float* __restrict__ ms) {
  const int g = blockIdx.x, c = threadIdx.x;
  int s = starts[g], e = starts[g + 1];
  s = clampi(s, 0, N_NODES);
  e = clampi(e, s, N_NODES);
  const float cnt = (float)((e - s) > 1 ? (e - s) : 1);
  float sx = 0.f, sxx = 0.f;
  for (int i = s; i < e; ++i) {
    float xv = (float)v[(size_t)i * H + c];
    sx += xv; sxx += xv * xv;
  }
  const float mean = sx / cnt;
  const float sub = ms[c] * mean;
  float var = sxx / cnt - 2.f * sub * mean + sub * sub;
  var = fmaxf(var, 0.f);
  const float inv = rsqrtf(var + 1e-5f) * w[c];
  const float bb = b[c];
  for (int i = s; i < e; ++i) {
    float o = ((float)v[(size_t)i * H + c] - sub) * inv + bb;
    hout[(size_t)i * H + c] = (bf16_t)(o > 0.f ? o : 0.f);
  }
}

// ---------------- global mean pool -> fp32 (direct to d_out) --------------
__global__ void pool_kernel(const bf16_t* __restrict__ h, const int* __restrict__ starts,
                            float* __restrict__ hg) {
  const int g = blockIdx.x, c = threadIdx.x;
  int s = starts[g], e = starts[g + 1];
  s = clampi(s, 0, N_NODES);
  e = clampi(e, s, N_NODES);
  const float cnt = (float)((e - s) > 1 ? (e - s) : 1);
  float sum = 0.f;
  for (int i = s; i < e; ++i) sum += (float)h[(size_t)i * H + c];
  hg[(size_t)g * H + c] = sum / cnt;
}

// ---------------- small dense: Out[M x Nc] = act(In@W + b), all fp32 ------
__global__ void small_gemm_kernel(const float* __restrict__ In, const float* __restrict__ W,
                                  const float* __restrict__ bias, float* __restrict__ Out,
                                  int M, int K, int Nc, int relu) {
  int idx = blockIdx.x * blockDim.x + threadIdx.x;
  if (idx >= M * Nc) return;
  int r = idx / Nc, n = idx - r * Nc;
  float acc = bias[n];
  const float* in = In + (size_t)r * K;
  for (int k = 0; k < K; ++k) acc += in[k] * W[(size_t)k * Nc + n];
  if (relu && acc < 0.f) acc = 0.f;
  Out[idx] = acc;
}

extern "C" void kernel_launch(void* const* d_in, const int* in_sizes, int n_in,
                              void* d_out, int out_size, void* d_ws, size_t ws_size,
                              hipStream_t stream) {
  (void)in_sizes; (void)n_in; (void)out_size; (void)ws_size;
  const float* x        = (const float*)d_in[0];
  const int*   eidx     = (const int*)d_in[1];
  const float* eattr    = (const float*)d_in[2];
  const int*   batch    = (const int*)d_in[3];
  const float* node_W   = (const float*)d_in[4];
  const float* node_b   = (const float*)d_in[5];
  const float* conv_eps = (const float*)d_in[6];
  const float* edge_W   = (const float*)d_in[7];
  const float* edge_b   = (const float*)d_in[8];
  const float* mlp_W1   = (const float*)d_in[9];
  const float* mlp_b1   = (const float*)d_in[10];
  const float* mlp_W2   = (const float*)d_in[11];
  const float* mlp_b2   = (const float*)d_in[12];
  const float* gn_w     = (const float*)d_in[13];
  const float* gn_b     = (const float*)d_in[14];
  const float* gn_ms    = (const float*)d_in[15];
  const float* finv_W1  = (const float*)d_in[16];
  const float* finv_b1  = (const float*)d_in[17];
  const float* finv_W2  = (const float*)d_in[18];
  const float* finv_b2  = (const float*)d_in[19];
  const float* fspu_W1  = (const float*)d_in[20];
  const float* fspu_b1  = (const float*)d_in[21];
  const float* fspu_W2  = (const float*)d_in[22];
  const float* fspu_b2  = (const float*)d_in[23];
  const float* pred_W1  = (const float*)d_in[24];
  const float* pred_b1  = (const float*)d_in[25];
  const float* pred_W2  = (const float*)d_in[26];
  const float* pred_b2  = (const float*)d_in[27];
  const float* adv_W1   = (const float*)d_in[28];
  const float* adv_b1   = (const float*)d_in[29];
  const float* adv_W2   = (const float*)d_in[30];
  const float* adv_b2   = (const float*)d_in[31];
  float* out = (float*)d_out;

  // d_out slices (fp32, written in place; hg/zi reused as head inputs)
  float* out_hg = out;                                  // [G,H]
  float* out_zi = out + (size_t)N_GRAPH * H;            // [G,ZI]
  float* out_zs = out_zi + (size_t)N_GRAPH * ZIC;       // [G,ZS]
  float* out_yh = out_zs + (size_t)N_GRAPH * ZIC;       // [G]
  float* out_ev = out_yh + N_GRAPH;                     // [G,NE]

  // workspace carve-up (~112 MiB total)
  char* wp = (char*)d_ws;
  auto alloc = [&](size_t bytes) { char* p = wp; wp += (bytes + 255) & ~(size_t)255; return p; };
  bf16_t* A       = (bf16_t*)alloc((size_t)N_NODES * H * 2);   // h / t
  bf16_t* B       = (bf16_t*)alloc((size_t)N_NODES * H * 2);   // u / v
  bf16_t* Wt      = (bf16_t*)alloc((size_t)(H * ND + 6 * H * H) * 2);
  int*    starts  = (int*)alloc((size_t)(N_GRAPH + 1) * 4);
  int*    counts  = (int*)alloc((size_t)N_NODES * 4);
  int*    cursor  = (int*)alloc((size_t)N_NODES * 4);
  int*    offs    = (int*)alloc((size_t)(N_NODES + 1) * 4);
  int*    bsum    = (int*)alloc((size_t)SCAN_B * 4);
  int*    perm    = (int*)alloc((size_t)N_EDGES * 4);
  int*    src_srt = (int*)alloc((size_t)N_EDGES * 4);
  float*  tmp1    = (float*)alloc((size_t)N_GRAPH * ZIC * 4);
  float*  tmp2    = (float*)alloc((size_t)N_GRAPH * ZIC * 4);

  const int* srcp = eidx;
  const int* dstp = eidx + N_EDGES;
  const int nscan = (N_NODES + SCAN_B - 1) / SCAN_B;

  compute_starts_kernel<<<(N_NODES + 255) / 256, 256, 0, stream>>>(batch, starts, N_NODES, N_GRAPH);

  // CSR build (edges grouped by dst)
  zero2_kernel<<<(N_NODES + 255) / 256, 256, 0, stream>>>(counts, cursor, N_NODES);
  count_deg_kernel<<<(N_EDGES + 255) / 256, 256, 0, stream>>>(dstp, counts, N_EDGES, N_NODES);
  scan1_kernel<<<nscan, SCAN_B, 0, stream>>>(counts, offs, bsum, N_NODES);
  scan2_kernel<<<1, 64, 0, stream>>>(bsum, nscan);
  scan3_kernel<<<nscan, SCAN_B, 0, stream>>>(offs, bsum, N_NODES);
  fill_perm_kernel<<<(N_EDGES + 255) / 256, 256, 0, stream>>>(dstp, offs, cursor, perm, N_EDGES, N_NODES);
  sort_src_kernel<<<(N_EDGES + 255) / 256, 256, 0, stream>>>(perm, srcp, src_srt, N_EDGES);

  // transpose (+bf16-cast) all MFMA weights upfront
  bf16_t* WtN = Wt;
  auto Wt1l = [&](int l) { return Wt + H * ND + (size_t)(2 * l) * H * H; };
  auto Wt2l = [&](int l) { return Wt + H * ND + (size_t)(2 * l + 1) * H * H; };
  transpose_kernel<<<dim3(H / 32, ND / 32), dim3(32, 8), 0, stream>>>(node_W, WtN, ND, H);
  for (int l = 0; l < 3; ++l) {
    transpose_kernel<<<dim3(H / 32, H / 32), dim3(32, 8), 0, stream>>>(mlp_W1 + (size_t)l * H * H, Wt1l(l), H, H);
    transpose_kernel<<<dim3(H / 32, H / 32), dim3(32, 8), 0, stream>>>(mlp_W2 + (size_t)l * H * H, Wt2l(l), H, H);
  }

  dim3 ggrid((N_NODES + 63) / 64, H / 64);
  // h = x @ node_W + node_b  (fp32 x converted in staging) -> A (bf16)
  gemm_kernel<ND, false><<<ggrid, 256, 0, stream>>>(x, WtN, node_b, A, N_NODES, H);

  for (int l = 0; l < 3; ++l) {
    gine_gather_kernel<<<N_NODES, H, 0, stream>>>(A, eattr, src_srt, perm, offs,
                                                  edge_W + (size_t)l * ED * H,
                                                  edge_b + l * H, conv_eps + l, B);
    gemm_kernel<H, true ><<<ggrid, 256, 0, stream>>>(B, Wt1l(l), mlp_b1 + l * H, A, N_NODES, H);
    gemm_kernel<H, false><<<ggrid, 256, 0, stream>>>(A, Wt2l(l), mlp_b2 + l * H, B, N_NODES, H);
    graphnorm_kernel<<<N_GRAPH, H, 0, stream>>>(B, A, starts, gn_w + l * H, gn_b + l * H, gn_ms + l * H);
  }

  pool_kernel<<<N_GRAPH, H, 0, stream>>>(A, starts, out_hg);

  auto sg = [&](const float* In, const float* W, const float* b, float* Out,
                int M, int K, int Nc, int relu) {
    small_gemm_kernel<<<(M * Nc + 255) / 256, 256, 0, stream>>>(In, W, b, Out, M, K, Nc, relu);
  };
  sg(out_hg, finv_W1, finv_b1, tmp1,   N_GRAPH, H,   ZIC, 1);
  sg(tmp1,   finv_W2, finv_b2, out_zi, N_GRAPH, ZIC, ZIC, 0);
  sg(out_hg, fspu_W1, fspu_b1, tmp2,   N_GRAPH, H,   ZIC, 1);
  sg(tmp2,   fspu_W2, fspu_b2, out_zs, N_GRAPH, ZIC, ZIC, 0);
  sg(out_zi, pred_W1, pred_b1, tmp1,   N_GRAPH, ZIC, ZIC, 1);
  sg(tmp1,   pred_W2, pred_b2, out_yh, N_GRAPH, ZIC, 1,   0);
  sg(out_zi, adv_W1,  adv_b1,  tmp2,   N_GRAPH, ZIC, ZIC, 1);
  sg(tmp2,   adv_W2,  adv_b2,  out_ev, N_GRAPH, ZIC, NE,  0);
}

// Round 7
// 1000.720 us; speedup vs baseline: 1.6645x; 1.4627x over previous
//
#include <hip/hip_runtime.h>
#include <hip/hip_bf16.h>

typedef __bf16 bf16_t;
typedef __bf16 bf16x8 __attribute__((ext_vector_type(8)));
typedef __bf16 bf16x4 __attribute__((ext_vector_type(4)));
typedef float  f32x4  __attribute__((ext_vector_type(4)));

static constexpr int N_NODES = 100000;
static constexpr int N_EDGES = 300000;
static constexpr int N_GRAPH = 4096;
static constexpr int H  = 256;
static constexpr int ND = 64;
static constexpr int ZIC = 128;
static constexpr int NE = 8;
static constexpr int SCAN_B = 1024;

__device__ __forceinline__ int clampi(int v, int lo, int hi) {
  return v < lo ? lo : (v > hi ? hi : v);
}

// ---------------- graph segment starts (batch is sorted) ----------------
__global__ void compute_starts_kernel(const int* __restrict__ batch,
                                      int* __restrict__ starts, int N, int G) {
  int i = blockIdx.x * blockDim.x + threadIdx.x;
  if (i >= N) return;
  int b = clampi(batch[i], 0, G - 1);
  if (i == 0) {
    for (int g = 0; g <= b; ++g) starts[g] = 0;
  } else {
    int p = clampi(batch[i - 1], 0, G - 1);
    for (int g = p + 1; g <= b; ++g) starts[g] = i;
  }
  if (i == N - 1) {
    for (int g = b + 1; g <= G; ++g) starts[g] = N;
  }
}

// ---------------- CSR build ----------------
__global__ void zero2_kernel(int* __restrict__ a, int* __restrict__ b, int N) {
  int i = blockIdx.x * blockDim.x + threadIdx.x;
  if (i < N) { a[i] = 0; b[i] = 0; }
}

__global__ void count_deg_kernel(const int* __restrict__ dst, int* __restrict__ counts, int E, int N) {
  int e = blockIdx.x * blockDim.x + threadIdx.x;
  if (e < E) atomicAdd(&counts[clampi(dst[e], 0, N - 1)], 1);
}

__global__ __launch_bounds__(SCAN_B) void scan1_kernel(const int* __restrict__ counts,
                                                       int* __restrict__ offs,
                                                       int* __restrict__ bsum, int N) {
  __shared__ int tmp[SCAN_B];
  int i = blockIdx.x * SCAN_B + threadIdx.x;
  int v = (i < N) ? counts[i] : 0;
  tmp[threadIdx.x] = v;
  __syncthreads();
  for (int d = 1; d < SCAN_B; d <<= 1) {
    int t = (threadIdx.x >= d) ? tmp[threadIdx.x - d] : 0;
    __syncthreads();
    tmp[threadIdx.x] += t;
    __syncthreads();
  }
  if (i < N) offs[i + 1] = tmp[threadIdx.x];
  if (threadIdx.x == SCAN_B - 1) bsum[blockIdx.x] = tmp[SCAN_B - 1];
  if (i == 0) offs[0] = 0;
}

__global__ void scan2_kernel(int* __restrict__ bsum, int nblk) {
  if (blockIdx.x == 0 && threadIdx.x == 0) {
    int run = 0;
    for (int b = 0; b < nblk; ++b) { int v = bsum[b]; bsum[b] = run; run += v; }
  }
}

__global__ __launch_bounds__(SCAN_B) void scan3_kernel(int* __restrict__ offs,
                                                       const int* __restrict__ bsum, int N) {
  int i = blockIdx.x * SCAN_B + threadIdx.x;
  if (i < N) offs[i + 1] += bsum[blockIdx.x];
}

__global__ void fill_perm_kernel(const int* __restrict__ dst, const int* __restrict__ offs,
                                 int* __restrict__ cursor, int* __restrict__ perm, int E, int N) {
  int e = blockIdx.x * blockDim.x + threadIdx.x;
  if (e >= E) return;
  int d = clampi(dst[e], 0, N - 1);
  int pos = offs[d] + atomicAdd(&cursor[d], 1);
  if ((unsigned)pos < (unsigned)E) perm[pos] = e;
}

__global__ void sort_src_kernel(const int* __restrict__ perm, const int* __restrict__ src,
                                int* __restrict__ src_sorted, int E) {
  int p = blockIdx.x * blockDim.x + threadIdx.x;
  if (p >= E) return;
  int e = perm[p];
  e = ((unsigned)e < (unsigned)E) ? e : 0;
  int s = src[e];
  src_sorted[p] = ((unsigned)s < (unsigned)N_NODES) ? s : 0;
}

// eattr gathered to dst-sorted order, bf16, 16 per row
__global__ void build_eattr16_kernel(const float* __restrict__ eattr,
                                     const int* __restrict__ perm,
                                     bf16_t* __restrict__ ep, int E) {
  int idx = blockIdx.x * blockDim.x + threadIdx.x;
  if (idx >= E * 16) return;
  int p = idx >> 4, k = idx & 15;
  int e = perm[p];
  e = ((unsigned)e < (unsigned)E) ? e : 0;
  ep[idx] = (bf16_t)eattr[(size_t)e * 16 + k];
}

// edge_W[l] (16 x 256) -> eWt[l] (256 rows x 16 cols), bf16
__global__ void build_ewt16_kernel(const float* __restrict__ edge_W,
                                   bf16_t* __restrict__ ewt) {
  int idx = blockIdx.x * blockDim.x + threadIdx.x;
  if (idx >= 3 * 256 * 16) return;
  int l = idx / (256 * 16);
  int rem = idx - l * 256 * 16;
  int n = rem >> 4, k = rem & 15;
  ewt[idx] = (bf16_t)edge_W[(size_t)l * 16 * 256 + k * 256 + n];
}

// -------- fp32 transpose + bf16 cast: W[K x Nc] -> Wt[Nc x K] (bf16) ------
__global__ void transpose_kernel(const float* __restrict__ W,
                                 bf16_t* __restrict__ Wt, int K, int Nc) {
  __shared__ float tile[32][33];
  int n0 = blockIdx.x * 32, k0 = blockIdx.y * 32;
  int tx = threadIdx.x, ty = threadIdx.y;
  for (int i = ty; i < 32; i += 8)
    tile[i][tx] = W[(size_t)(k0 + i) * Nc + n0 + tx];
  __syncthreads();
  for (int i = ty; i < 32; i += 8)
    Wt[(size_t)(n0 + i) * K + k0 + tx] = (bf16_t)tile[tx][i];
}

// ---- staging loaders: 8 contiguous elements -> 8 bf16 (16B) in LDS ----
__device__ __forceinline__ void load8_to_lds(const bf16_t* p, bool valid, uint4* dst) {
  uint4 v = make_uint4(0u, 0u, 0u, 0u);
  if (valid) v = *(const uint4*)p;
  *dst = v;
}
__device__ __forceinline__ void load8_to_lds(const float* p, bool valid, uint4* dst) {
  float4 f0 = make_float4(0.f, 0.f, 0.f, 0.f), f1 = f0;
  if (valid) { f0 = *(const float4*)p; f1 = *(const float4*)(p + 4); }
  union { bf16_t b[8]; uint4 u; } pk;
  pk.b[0] = (bf16_t)f0.x; pk.b[1] = (bf16_t)f0.y;
  pk.b[2] = (bf16_t)f0.z; pk.b[3] = (bf16_t)f0.w;
  pk.b[4] = (bf16_t)f1.x; pk.b[5] = (bf16_t)f1.y;
  pk.b[6] = (bf16_t)f1.z; pk.b[7] = (bf16_t)f1.w;
  *dst = pk.u;
}

// ---------------- MFMA GEMM 128x128, BK=64: Out = act(U @ W + bias) ------
// U row-major [M x K] (fp32 or bf16); Wt bf16 [Nc x K]; Nc multiple of 128.
// 4 waves 2x2, each wave 64x64 (4x4 of 16x16x32 mfma).
// Frags (guide §3, m89/m91/m92): A: m=lane&15,k=quad*8+j; B: n=lane&15,
// k=quad*8+j; D: col=lane&15, row=quad*4+r.
template<int K, bool RELU, bool OUTF32, typename TIN>
__global__ __launch_bounds__(256) void gemm128_kernel(
    const TIN* __restrict__ U, const bf16_t* __restrict__ Wt,
    const float* __restrict__ bias, void* __restrict__ Out, int M, int Nc) {
  constexpr int LDT = 72;  // 144B rows: 16B-aligned; 2-way banks (free, m136)
  __shared__ bf16_t Ut[128 * LDT];
  __shared__ bf16_t Wl[128 * LDT];
  const int m0 = blockIdx.x * 128;
  const int n0 = blockIdx.y * 128;
  const int t = threadIdx.x;
  const int lane = t & 63;
  const int wave = t >> 6;
  const int wm = (wave >> 1) * 64;
  const int wn = (wave & 1) * 64;
  const int srow = t >> 1;        // 0..127
  const int sk = (t & 1) * 32;    // 0 or 32
  const int lr = lane & 15;
  const int lq = lane >> 4;
  const bool aok = (m0 + srow) < M;
  f32x4 acc[4][4] = {};

  for (int k0 = 0; k0 < K; k0 += 64) {
    const TIN* up = U + (size_t)(m0 + srow) * K + k0 + sk;
    const bf16_t* wp = Wt + (size_t)(n0 + srow) * K + k0 + sk;
#pragma unroll
    for (int q = 0; q < 4; ++q) {
      load8_to_lds(up + q * 8, aok, (uint4*)&Ut[srow * LDT + sk + q * 8]);
      load8_to_lds(wp + q * 8, true, (uint4*)&Wl[srow * LDT + sk + q * 8]);
    }
    __syncthreads();
#pragma unroll
    for (int s = 0; s < 2; ++s) {
      bf16x8 a[4], b[4];
#pragma unroll
      for (int mt = 0; mt < 4; ++mt)
        a[mt] = *(const bf16x8*)(&Ut[(wm + mt * 16 + lr) * LDT + s * 32 + lq * 8]);
#pragma unroll
      for (int nt = 0; nt < 4; ++nt)
        b[nt] = *(const bf16x8*)(&Wl[(wn + nt * 16 + lr) * LDT + s * 32 + lq * 8]);
#pragma unroll
      for (int mt = 0; mt < 4; ++mt)
#pragma unroll
        for (int nt = 0; nt < 4; ++nt)
          acc[mt][nt] = __builtin_amdgcn_mfma_f32_16x16x32_bf16(
              a[mt], b[nt], acc[mt][nt], 0, 0, 0);
    }
    __syncthreads();
  }

#pragma unroll
  for (int mt = 0; mt < 4; ++mt)
#pragma unroll
    for (int nt = 0; nt < 4; ++nt) {
      int col = n0 + wn + nt * 16 + lr;
      float bcol = bias[col];
#pragma unroll
      for (int r = 0; r < 4; ++r) {
        int row = m0 + wm + mt * 16 + lq * 4 + r;
        if (row < M) {
          float vv = acc[mt][nt][r] + bcol;
          if (RELU) vv = vv > 0.f ? vv : 0.f;
          if (OUTF32) ((float*)Out)[(size_t)row * Nc + col] = vv;
          else        ((bf16_t*)Out)[(size_t)row * Nc + col] = (bf16_t)vv;
        }
      }
    }
}

// ---------------- fused GINE gather with MFMA edge-linear ----------------
// 4 nodes per block (wave per node). Per 16-edge chunk: all 4 waves compute
// lin = eattr_chunk @ eWt (each wave a 64-col slice) via mfma into LDS,
// then each wave consumes its node's edges in the chunk:
//   acc += relu(h[src] + lin + eb);  u = (1+eps)*h_self + acc
// K=16 real; upper half (k>=16) of A and B frags zeroed in registers.
__global__ __launch_bounds__(256) void gine_gather_mfma_kernel(
    const bf16_t* __restrict__ h, const bf16_t* __restrict__ eat16,
    const int* __restrict__ src_sorted, const int* __restrict__ offs,
    const bf16_t* __restrict__ ewt, const float* __restrict__ eb,
    const float* __restrict__ eps_p, bf16_t* __restrict__ u) {
  __shared__ bf16_t slin[16 * H];   // 8 KB
  const int t = threadIdx.x;
  const int wave = t >> 6;
  const int lane = t & 63;
  const int lr = lane & 15;
  const int lq = lane >> 4;
  const int lane4 = lane * 4;
  const int n0 = blockIdx.x * 4;
  const int nodeN = n0 + wave;

  // B frags: wave covers output cols [wave*64, wave*64+64), 4 n-tiles
  bf16x8 bfrag[4];
#pragma unroll
  for (int nt = 0; nt < 4; ++nt) {
    bf16x8 bv = {};
    if (lq < 2)
      bv = *(const bf16x8*)(ewt + ((wave * 64 + nt * 16 + lr) << 4) + (lq << 3));
    bfrag[nt] = bv;
  }
  float ebv[4];
#pragma unroll
  for (int i = 0; i < 4; ++i) ebv[i] = eb[lane4 + i];

  int bs = offs[n0], be = offs[n0 + 4];
  bs = clampi(bs, 0, N_EDGES);
  be = clampi(be, bs, N_EDGES);
  int ns = offs[nodeN], ne = offs[nodeN + 1];
  ns = clampi(ns, bs, be);
  ne = clampi(ne, ns, be);

  float acc[4] = {0.f, 0.f, 0.f, 0.f};

  for (int cb = bs; cb < be; cb += 16) {
    // MFMA: lin rows cb..cb+15, this wave's 64 cols
    int arow = cb + lr;
    if (arow >= N_EDGES) arow = N_EDGES - 1;
    bf16x8 afrag = {};
    if (lq < 2)
      afrag = *(const bf16x8*)(eat16 + ((size_t)arow << 4) + (lq << 3));
    f32x4 c[4];
#pragma unroll
    for (int nt = 0; nt < 4; ++nt) {
      f32x4 z = {};
      c[nt] = __builtin_amdgcn_mfma_f32_16x16x32_bf16(afrag, bfrag[nt], z, 0, 0, 0);
    }
    __syncthreads();   // protect prior chunk's consume before overwrite
#pragma unroll
    for (int nt = 0; nt < 4; ++nt)
#pragma unroll
      for (int r = 0; r < 4; ++r)
        slin[(lq * 4 + r) * H + wave * 64 + nt * 16 + lr] = (bf16_t)c[nt][r];
    __syncthreads();
    // consume this wave's node's edges within [cb, cb+16)
    int j0 = ns > cb ? ns : cb;
    int j1 = ne < cb + 16 ? ne : cb + 16;
    for (int j = j0; j < j1; ++j) {
      int s = src_sorted[j];
      bf16x4 hv = *(const bf16x4*)(h + (size_t)s * H + lane4);
      bf16x4 lv = *(const bf16x4*)(&slin[(j - cb) * H + lane4]);
#pragma unroll
      for (int i = 0; i < 4; ++i)
        acc[i] += fmaxf((float)hv[i] + (float)lv[i] + ebv[i], 0.f);
    }
  }

  const float sc = 1.0f + eps_p[0];
  bf16x4 hs = *(const bf16x4*)(h + (size_t)nodeN * H + lane4);
  union { bf16x4 v; uint2 b; } o;
#pragma unroll
  for (int i = 0; i < 4; ++i) o.v[i] = (bf16_t)(sc * (float)hs[i] + acc[i]);
  *(uint2*)(u + (size_t)nodeN * H + lane4) = o.b;
}

// ---------------- GraphNorm (+relu) 2-pass, one block/graph ----------------
__global__ void graphnorm_kernel(const bf16_t* __restrict__ v, bf16_t* __restrict__ hout,
                                 const int* __restrict__ starts,
                                 const float* __restrict__ w, const float* __restrict__ b,
                                 const float* __restrict__ ms) {
  const int g = blockIdx.x, c = threadIdx.x;
  int s = starts[g], e = starts[g + 1];
  s = clampi(s, 0, N_NODES);
  e = clampi(e, s, N_NODES);
  const float cnt = (float)((e - s) > 1 ? (e - s) : 1);
  float sx = 0.f, sxx = 0.f;
  for (int i = s; i < e; ++i) {
    float xv = (float)v[(size_t)i * H + c];
    sx += xv; sxx += xv * xv;
  }
  const float mean = sx / cnt;
  const float sub = ms[c] * mean;
  float var = sxx / cnt - 2.f * sub * mean + sub * sub;
  var = fmaxf(var, 0.f);
  const float inv = rsqrtf(var + 1e-5f) * w[c];
  const float bb = b[c];
  for (int i = s; i < e; ++i) {
    float o = ((float)v[(size_t)i * H + c] - sub) * inv + bb;
    hout[(size_t)i * H + c] = (bf16_t)(o > 0.f ? o : 0.f);
  }
}

// ---------------- global mean pool -> fp32 (direct to d_out) --------------
__global__ void pool_kernel(const bf16_t* __restrict__ h, const int* __restrict__ starts,
                            float* __restrict__ hg) {
  const int g = blockIdx.x, c = threadIdx.x;
  int s = starts[g], e = starts[g + 1];
  s = clampi(s, 0, N_NODES);
  e = clampi(e, s, N_NODES);
  const float cnt = (float)((e - s) > 1 ? (e - s) : 1);
  float sum = 0.f;
  for (int i = s; i < e; ++i) sum += (float)h[(size_t)i * H + c];
  hg[(size_t)g * H + c] = sum / cnt;
}

// ---- tiny tail heads (Nc=1 / Nc=8): Out[M x Nc] = In(bf16) @ W + b -------
__global__ void head_out_kernel(const bf16_t* __restrict__ In, const float* __restrict__ W,
                                const float* __restrict__ bias, float* __restrict__ Out,
                                int M, int K, int Nc) {
  int idx = blockIdx.x * blockDim.x + threadIdx.x;
  if (idx >= M * Nc) return;
  int r = idx / Nc, n = idx - r * Nc;
  float acc = bias[n];
  const bf16_t* in = In + (size_t)r * K;
  for (int k = 0; k < K; ++k) acc += (float)in[k] * W[(size_t)k * Nc + n];
  Out[idx] = acc;
}

extern "C" void kernel_launch(void* const* d_in, const int* in_sizes, int n_in,
                              void* d_out, int out_size, void* d_ws, size_t ws_size,
                              hipStream_t stream) {
  (void)in_sizes; (void)n_in; (void)out_size; (void)ws_size;
  const float* x        = (const float*)d_in[0];
  const int*   eidx     = (const int*)d_in[1];
  const float* eattr    = (const float*)d_in[2];
  const int*   batch    = (const int*)d_in[3];
  const float* node_W   = (const float*)d_in[4];
  const float* node_b   = (const float*)d_in[5];
  const float* conv_eps = (const float*)d_in[6];
  const float* edge_W   = (const float*)d_in[7];
  const float* edge_b   = (const float*)d_in[8];
  const float* mlp_W1   = (const float*)d_in[9];
  const float* mlp_b1   = (const float*)d_in[10];
  const float* mlp_W2   = (const float*)d_in[11];
  const float* mlp_b2   = (const float*)d_in[12];
  const float* gn_w     = (const float*)d_in[13];
  const float* gn_b     = (const float*)d_in[14];
  const float* gn_ms    = (const float*)d_in[15];
  const float* finv_W1  = (const float*)d_in[16];
  const float* finv_b1  = (const float*)d_in[17];
  const float* finv_W2  = (const float*)d_in[18];
  const float* finv_b2  = (const float*)d_in[19];
  const float* fspu_W1  = (const float*)d_in[20];
  const float* fspu_b1  = (const float*)d_in[21];
  const float* fspu_W2  = (const float*)d_in[22];
  const float* fspu_b2  = (const float*)d_in[23];
  const float* pred_W1  = (const float*)d_in[24];
  const float* pred_b1  = (const float*)d_in[25];
  const float* pred_W2  = (const float*)d_in[26];
  const float* pred_b2  = (const float*)d_in[27];
  const float* adv_W1   = (const float*)d_in[28];
  const float* adv_b1   = (const float*)d_in[29];
  const float* adv_W2   = (const float*)d_in[30];
  const float* adv_b2   = (const float*)d_in[31];
  float* out = (float*)d_out;

  float* out_hg = out;                                  // [G,H]
  float* out_zi = out + (size_t)N_GRAPH * H;            // [G,ZI]
  float* out_zs = out_zi + (size_t)N_GRAPH * ZIC;       // [G,ZS]
  float* out_yh = out_zs + (size_t)N_GRAPH * ZIC;       // [G]
  float* out_ev = out_yh + N_GRAPH;                     // [G,NE]

  // workspace carve-up (~119 MiB total)
  char* wp = (char*)d_ws;
  auto alloc = [&](size_t bytes) { char* p = wp; wp += (bytes + 255) & ~(size_t)255; return p; };
  bf16_t* A        = (bf16_t*)alloc((size_t)N_NODES * H * 2);   // h / t
  bf16_t* B        = (bf16_t*)alloc((size_t)N_NODES * H * 2);   // u / v
  bf16_t* Wt       = (bf16_t*)alloc((size_t)(H * ND + 6 * H * H) * 2);
  bf16_t* WtH      = (bf16_t*)alloc((size_t)(2 * ZIC * H + 4 * ZIC * ZIC) * 2); // head W^T
  bf16_t* ewt16    = (bf16_t*)alloc((size_t)3 * 256 * 16 * 2);
  bf16_t* eat16    = (bf16_t*)alloc((size_t)N_EDGES * 16 * 2);
  int*    starts   = (int*)alloc((size_t)(N_GRAPH + 1) * 4);
  int*    counts   = (int*)alloc((size_t)N_NODES * 4);
  int*    cursor   = (int*)alloc((size_t)N_NODES * 4);
  int*    offs     = (int*)alloc((size_t)(N_NODES + 1) * 4);
  int*    bsum     = (int*)alloc((size_t)SCAN_B * 4);
  int*    perm     = (int*)alloc((size_t)N_EDGES * 4);
  int*    src_srt  = (int*)alloc((size_t)N_EDGES * 4);
  bf16_t* tmp1     = (bf16_t*)alloc((size_t)N_GRAPH * ZIC * 2);
  bf16_t* tmp2     = (bf16_t*)alloc((size_t)N_GRAPH * ZIC * 2);

  const int* srcp = eidx;
  const int* dstp = eidx + N_EDGES;
  const int nscan = (N_NODES + SCAN_B - 1) / SCAN_B;

  compute_starts_kernel<<<(N_NODES + 255) / 256, 256, 0, stream>>>(batch, starts, N_NODES, N_GRAPH);

  // CSR build (edges grouped by dst)
  zero2_kernel<<<(N_NODES + 255) / 256, 256, 0, stream>>>(counts, cursor, N_NODES);
  count_deg_kernel<<<(N_EDGES + 255) / 256, 256, 0, stream>>>(dstp, counts, N_EDGES, N_NODES);
  scan1_kernel<<<nscan, SCAN_B, 0, stream>>>(counts, offs, bsum, N_NODES);
  scan2_kernel<<<1, 64, 0, stream>>>(bsum, nscan);
  scan3_kernel<<<nscan, SCAN_B, 0, stream>>>(offs, bsum, N_NODES);
  fill_perm_kernel<<<(N_EDGES + 255) / 256, 256, 0, stream>>>(dstp, offs, cursor, perm, N_EDGES, N_NODES);
  sort_src_kernel<<<(N_EDGES + 255) / 256, 256, 0, stream>>>(perm, srcp, src_srt, N_EDGES);
  build_eattr16_kernel<<<(N_EDGES * 16 + 255) / 256, 256, 0, stream>>>(eattr, perm, eat16, N_EDGES);
  build_ewt16_kernel<<<(3 * 256 * 16 + 255) / 256, 256, 0, stream>>>(edge_W, ewt16);

  // transpose (+bf16-cast) all MFMA weights upfront
  bf16_t* WtN = Wt;
  auto Wt1l = [&](int l) { return Wt + H * ND + (size_t)(2 * l) * H * H; };
  auto Wt2l = [&](int l) { return Wt + H * ND + (size_t)(2 * l + 1) * H * H; };
  transpose_kernel<<<dim3(H / 32, ND / 32), dim3(32, 8), 0, stream>>>(node_W, WtN, ND, H);
  for (int l = 0; l < 3; ++l) {
    transpose_kernel<<<dim3(H / 32, H / 32), dim3(32, 8), 0, stream>>>(mlp_W1 + (size_t)l * H * H, Wt1l(l), H, H);
    transpose_kernel<<<dim3(H / 32, H / 32), dim3(32, 8), 0, stream>>>(mlp_W2 + (size_t)l * H * H, Wt2l(l), H, H);
  }
  // head weight transposes: W[K x Nc] -> [Nc x K]
  bf16_t* fT1 = WtH;                          // [128 x 256]
  bf16_t* fT2 = fT1 + ZIC * H;                // [128 x 128]
  bf16_t* sT1 = fT2 + ZIC * ZIC;              // [128 x 256]
  bf16_t* sT2 = sT1 + ZIC * H;                // [128 x 128]
  bf16_t* pT1 = sT2 + ZIC * ZIC;              // [128 x 128]
  bf16_t* aT1 = pT1 + ZIC * ZIC;              // [128 x 128]  (fits: 2*ZIC*H+4*ZIC*ZIC)
  transpose_kernel<<<dim3(ZIC / 32, H / 32), dim3(32, 8), 0, stream>>>(finv_W1, fT1, H, ZIC);
  transpose_kernel<<<dim3(ZIC / 32, ZIC / 32), dim3(32, 8), 0, stream>>>(finv_W2, fT2, ZIC, ZIC);
  transpose_kernel<<<dim3(ZIC / 32, H / 32), dim3(32, 8), 0, stream>>>(fspu_W1, sT1, H, ZIC);
  transpose_kernel<<<dim3(ZIC / 32, ZIC / 32), dim3(32, 8), 0, stream>>>(fspu_W2, sT2, ZIC, ZIC);
  transpose_kernel<<<dim3(ZIC / 32, ZIC / 32), dim3(32, 8), 0, stream>>>(pred_W1, pT1, ZIC, ZIC);
  transpose_kernel<<<dim3(ZIC / 32, ZIC / 32), dim3(32, 8), 0, stream>>>(adv_W1, aT1, ZIC, ZIC);

  dim3 ggrid((N_NODES + 127) / 128, H / 128);
  // h = x @ node_W + node_b  (fp32 x converted in staging) -> A (bf16)
  gemm128_kernel<ND, false, false><<<ggrid, 256, 0, stream>>>(x, WtN, node_b, A, N_NODES, H);

  for (int l = 0; l < 3; ++l) {
    gine_gather_mfma_kernel<<<N_NODES / 4, 256, 0, stream>>>(
        A, eat16, src_srt, offs, ewt16 + (size_t)l * 256 * 16,
        edge_b + l * H, conv_eps + l, B);
    gemm128_kernel<H, true,  false><<<ggrid, 256, 0, stream>>>(B, Wt1l(l), mlp_b1 + l * H, A, N_NODES, H);
    gemm128_kernel<H, false, false><<<ggrid, 256, 0, stream>>>(A, Wt2l(l), mlp_b2 + l * H, B, N_NODES, H);
    graphnorm_kernel<<<N_GRAPH, H, 0, stream>>>(B, A, starts, gn_w + l * H, gn_b + l * H, gn_ms + l * H);
  }

  pool_kernel<<<N_GRAPH, H, 0, stream>>>(A, starts, out_hg);

  // heads via MFMA (M=4096, Nc=128): layer1 fp32-in -> bf16 tmp; layer2 -> fp32 d_out
  dim3 hgrid(N_GRAPH / 128, 1);
  gemm128_kernel<H,   true,  false><<<hgrid, 256, 0, stream>>>(out_hg, fT1, finv_b1, tmp1, N_GRAPH, ZIC);
  gemm128_kernel<ZIC, false, true ><<<hgrid, 256, 0, stream>>>(tmp1, fT2, finv_b2, out_zi, N_GRAPH, ZIC);
  gemm128_kernel<H,   true,  false><<<hgrid, 256, 0, stream>>>(out_hg, sT1, fspu_b1, tmp2, N_GRAPH, ZIC);
  gemm128_kernel<ZIC, false, true ><<<hgrid, 256, 0, stream>>>(tmp2, sT2, fspu_b2, out_zs, N_GRAPH, ZIC);
  gemm128_kernel<ZIC, true,  false><<<hgrid, 256, 0, stream>>>(out_zi, pT1, pred_b1, tmp1, N_GRAPH, ZIC);
  gemm128_kernel<ZIC, true,  false><<<hgrid, 256, 0, stream>>>(out_zi, aT1, adv_b1, tmp2, N_GRAPH, ZIC);
  head_out_kernel<<<(N_GRAPH + 255) / 256, 256, 0, stream>>>(tmp1, pred_W2, pred_b2, out_yh, N_GRAPH, ZIC, 1);
  head_out_kernel<<<(N_GRAPH * NE + 255) / 256, 256, 0, stream>>>(tmp2, adv_W2, adv_b2, out_ev, N_GRAPH, ZIC, NE);
}

// Round 8
// 932.757 us; speedup vs baseline: 1.7858x; 1.0729x over previous
//
#include <hip/hip_runtime.h>
#include <hip/hip_bf16.h>

typedef __bf16 bf16_t;
typedef __bf16 bf16x8 __attribute__((ext_vector_type(8)));
typedef __bf16 bf16x4 __attribute__((ext_vector_type(4)));
typedef float  f32x4  __attribute__((ext_vector_type(4)));

static constexpr int N_NODES = 100000;
static constexpr int N_EDGES = 300000;
static constexpr int N_GRAPH = 4096;
static constexpr int H  = 256;
static constexpr int ND = 64;
static constexpr int ZIC = 128;
static constexpr int NE = 8;
static constexpr int SCAN_B = 1024;

__device__ __forceinline__ int clampi(int v, int lo, int hi) {
  return v < lo ? lo : (v > hi ? hi : v);
}

// async 16B global -> LDS (wave-uniform LDS base + lane*16)
__device__ __forceinline__ void dma16(const bf16_t* g, bf16_t* lds_base) {
  __builtin_amdgcn_global_load_lds(
      (const __attribute__((address_space(1))) void*)g,
      (__attribute__((address_space(3))) void*)lds_base, 16, 0, 0);
}

// ---------------- graph segment starts (batch is sorted) ----------------
__global__ void compute_starts_kernel(const int* __restrict__ batch,
                                      int* __restrict__ starts, int N, int G) {
  int i = blockIdx.x * blockDim.x + threadIdx.x;
  if (i >= N) return;
  int b = clampi(batch[i], 0, G - 1);
  if (i == 0) {
    for (int g = 0; g <= b; ++g) starts[g] = 0;
  } else {
    int p = clampi(batch[i - 1], 0, G - 1);
    for (int g = p + 1; g <= b; ++g) starts[g] = i;
  }
  if (i == N - 1) {
    for (int g = b + 1; g <= G; ++g) starts[g] = N;
  }
}

// ---------------- CSR build ----------------
__global__ void zero2_kernel(int* __restrict__ a, int* __restrict__ b, int N) {
  int i = blockIdx.x * blockDim.x + threadIdx.x;
  if (i < N) { a[i] = 0; b[i] = 0; }
}

__global__ void count_deg_kernel(const int* __restrict__ dst, int* __restrict__ counts, int E, int N) {
  int e = blockIdx.x * blockDim.x + threadIdx.x;
  if (e < E) atomicAdd(&counts[clampi(dst[e], 0, N - 1)], 1);
}

__global__ __launch_bounds__(SCAN_B) void scan1_kernel(const int* __restrict__ counts,
                                                       int* __restrict__ offs,
                                                       int* __restrict__ bsum, int N) {
  __shared__ int tmp[SCAN_B];
  int i = blockIdx.x * SCAN_B + threadIdx.x;
  int v = (i < N) ? counts[i] : 0;
  tmp[threadIdx.x] = v;
  __syncthreads();
  for (int d = 1; d < SCAN_B; d <<= 1) {
    int t = (threadIdx.x >= d) ? tmp[threadIdx.x - d] : 0;
    __syncthreads();
    tmp[threadIdx.x] += t;
    __syncthreads();
  }
  if (i < N) offs[i + 1] = tmp[threadIdx.x];
  if (threadIdx.x == SCAN_B - 1) bsum[blockIdx.x] = tmp[SCAN_B - 1];
  if (i == 0) offs[0] = 0;
}

__global__ void scan2_kernel(int* __restrict__ bsum, int nblk) {
  if (blockIdx.x == 0 && threadIdx.x == 0) {
    int run = 0;
    for (int b = 0; b < nblk; ++b) { int v = bsum[b]; bsum[b] = run; run += v; }
  }
}

__global__ __launch_bounds__(SCAN_B) void scan3_kernel(int* __restrict__ offs,
                                                       const int* __restrict__ bsum, int N) {
  int i = blockIdx.x * SCAN_B + threadIdx.x;
  if (i < N) offs[i + 1] += bsum[blockIdx.x];
}

__global__ void fill_perm_kernel(const int* __restrict__ dst, const int* __restrict__ offs,
                                 int* __restrict__ cursor, int* __restrict__ perm, int E, int N) {
  int e = blockIdx.x * blockDim.x + threadIdx.x;
  if (e >= E) return;
  int d = clampi(dst[e], 0, N - 1);
  int pos = offs[d] + atomicAdd(&cursor[d], 1);
  if ((unsigned)pos < (unsigned)E) perm[pos] = e;
}

__global__ void sort_src_kernel(const int* __restrict__ perm, const int* __restrict__ src,
                                int* __restrict__ src_sorted, int E) {
  int p = blockIdx.x * blockDim.x + threadIdx.x;
  if (p >= E) return;
  int e = perm[p];
  e = ((unsigned)e < (unsigned)E) ? e : 0;
  int s = src[e];
  src_sorted[p] = ((unsigned)s < (unsigned)N_NODES) ? s : 0;
}

// eattr gathered to dst-sorted order, bf16, 16 per row
__global__ void build_eattr16_kernel(const float* __restrict__ eattr,
                                     const int* __restrict__ perm,
                                     bf16_t* __restrict__ ep, int E) {
  int idx = blockIdx.x * blockDim.x + threadIdx.x;
  if (idx >= E * 16) return;
  int p = idx >> 4, k = idx & 15;
  int e = perm[p];
  e = ((unsigned)e < (unsigned)E) ? e : 0;
  ep[idx] = (bf16_t)eattr[(size_t)e * 16 + k];
}

// edge_W[l] (16 x 256) -> eWt[l] (256 rows x 16 cols), bf16
__global__ void build_ewt16_kernel(const float* __restrict__ edge_W,
                                   bf16_t* __restrict__ ewt) {
  int idx = blockIdx.x * blockDim.x + threadIdx.x;
  if (idx >= 3 * 256 * 16) return;
  int l = idx / (256 * 16);
  int rem = idx - l * 256 * 16;
  int n = rem >> 4, k = rem & 15;
  ewt[idx] = (bf16_t)edge_W[(size_t)l * 16 * 256 + k * 256 + n];
}

// -------- fp32 transpose + bf16 cast: W[K x Nc] -> Wt[Nc x K] (bf16) ------
__global__ void transpose_kernel(const float* __restrict__ W,
                                 bf16_t* __restrict__ Wt, int K, int Nc) {
  __shared__ float tile[32][33];
  int n0 = blockIdx.x * 32, k0 = blockIdx.y * 32;
  int tx = threadIdx.x, ty = threadIdx.y;
  for (int i = ty; i < 32; i += 8)
    tile[i][tx] = W[(size_t)(k0 + i) * Nc + n0 + tx];
  __syncthreads();
  for (int i = ty; i < 32; i += 8)
    Wt[(size_t)(n0 + i) * K + k0 + tx] = (bf16_t)tile[tx][i];
}

// ---- staging loaders: 8 contiguous elements -> 8 bf16 (16B) in LDS ----
__device__ __forceinline__ void load8_to_lds(const bf16_t* p, bool valid, uint4* dst) {
  uint4 v = make_uint4(0u, 0u, 0u, 0u);
  if (valid) v = *(const uint4*)p;
  *dst = v;
}
__device__ __forceinline__ void load8_to_lds(const float* p, bool valid, uint4* dst) {
  float4 f0 = make_float4(0.f, 0.f, 0.f, 0.f), f1 = f0;
  if (valid) { f0 = *(const float4*)p; f1 = *(const float4*)(p + 4); }
  union { bf16_t b[8]; uint4 u; } pk;
  pk.b[0] = (bf16_t)f0.x; pk.b[1] = (bf16_t)f0.y;
  pk.b[2] = (bf16_t)f0.z; pk.b[3] = (bf16_t)f0.w;
  pk.b[4] = (bf16_t)f1.x; pk.b[5] = (bf16_t)f1.y;
  pk.b[6] = (bf16_t)f1.z; pk.b[7] = (bf16_t)f1.w;
  *dst = pk.u;
}

// ---------------- MFMA GEMM 128x128 (fp32 input, VGPR staging) -----------
template<int K, bool RELU, bool OUTF32, typename TIN>
__global__ __launch_bounds__(256) void gemm128_kernel(
    const TIN* __restrict__ U, const bf16_t* __restrict__ Wt,
    const float* __restrict__ bias, void* __restrict__ Out, int M, int Nc) {
  constexpr int LDT = 72;
  __shared__ bf16_t Ut[128 * LDT];
  __shared__ bf16_t Wl[128 * LDT];
  const int m0 = blockIdx.x * 128;
  const int n0 = blockIdx.y * 128;
  const int t = threadIdx.x;
  const int lane = t & 63;
  const int wave = t >> 6;
  const int wm = (wave >> 1) * 64;
  const int wn = (wave & 1) * 64;
  const int srow = t >> 1;
  const int sk = (t & 1) * 32;
  const int lr = lane & 15;
  const int lq = lane >> 4;
  const bool aok = (m0 + srow) < M;
  f32x4 acc[4][4] = {};

  for (int k0 = 0; k0 < K; k0 += 64) {
    const TIN* up = U + (size_t)(m0 + srow) * K + k0 + sk;
    const bf16_t* wp = Wt + (size_t)(n0 + srow) * K + k0 + sk;
#pragma unroll
    for (int q = 0; q < 4; ++q) {
      load8_to_lds(up + q * 8, aok, (uint4*)&Ut[srow * LDT + sk + q * 8]);
      load8_to_lds(wp + q * 8, true, (uint4*)&Wl[srow * LDT + sk + q * 8]);
    }
    __syncthreads();
#pragma unroll
    for (int s = 0; s < 2; ++s) {
      bf16x8 a[4], b[4];
#pragma unroll
      for (int mt = 0; mt < 4; ++mt)
        a[mt] = *(const bf16x8*)(&Ut[(wm + mt * 16 + lr) * LDT + s * 32 + lq * 8]);
#pragma unroll
      for (int nt = 0; nt < 4; ++nt)
        b[nt] = *(const bf16x8*)(&Wl[(wn + nt * 16 + lr) * LDT + s * 32 + lq * 8]);
#pragma unroll
      for (int mt = 0; mt < 4; ++mt)
#pragma unroll
        for (int nt = 0; nt < 4; ++nt)
          acc[mt][nt] = __builtin_amdgcn_mfma_f32_16x16x32_bf16(
              a[mt], b[nt], acc[mt][nt], 0, 0, 0);
    }
    __syncthreads();
  }

#pragma unroll
  for (int mt = 0; mt < 4; ++mt)
#pragma unroll
    for (int nt = 0; nt < 4; ++nt) {
      int col = n0 + wn + nt * 16 + lr;
      float bcol = bias[col];
#pragma unroll
      for (int r = 0; r < 4; ++r) {
        int row = m0 + wm + mt * 16 + lq * 4 + r;
        if (row < M) {
          float vv = acc[mt][nt][r] + bcol;
          if (RELU) vv = vv > 0.f ? vv : 0.f;
          if (OUTF32) ((float*)Out)[(size_t)row * Nc + col] = vv;
          else        ((bf16_t*)Out)[(size_t)row * Nc + col] = (bf16_t)vv;
        }
      }
    }
}

// ------- MFMA GEMM 128x128, bf16 input, global_load_lds + XOR swizzle -----
// LDS: unpadded 128 rows x 64 bf16; logical chunk lc (8 bf16) of row r is
// stored at physical chunk lc ^ (r&7). Staging: wave w, instr q covers rows
// q*32+w*8 .. +8; lane i -> row +(i>>3), phys chunk (i&7), so it must FETCH
// logical chunk (i&7)^(i>>3) from global. M-tail: clamp source row (rows
// >= M never written in epilogue).
template<int K, bool RELU, bool OUTF32>
__global__ __launch_bounds__(256) void gemm128_dma_kernel(
    const bf16_t* __restrict__ U, const bf16_t* __restrict__ Wt,
    const float* __restrict__ bias, void* __restrict__ Out, int M, int Nc) {
  __shared__ bf16_t Ut[128 * 64];
  __shared__ bf16_t Wl[128 * 64];
  const int t = threadIdx.x;
  const int lane = t & 63;
  const int wave = t >> 6;
  const int m0 = blockIdx.x * 128;
  const int n0 = blockIdx.y * 128;
  const int wm = (wave >> 1) * 64;
  const int wn = (wave & 1) * 64;
  const int lr = lane & 15;
  const int lq = lane >> 4;
  const int subrow = wave * 8 + (lane >> 3);        // + q*32
  const int lchunk = (lane & 7) ^ (lane >> 3);      // logical chunk to fetch
  f32x4 acc[4][4] = {};

  for (int k0 = 0; k0 < K; k0 += 64) {
#pragma unroll
    for (int q = 0; q < 4; ++q) {
      const int row = q * 32 + subrow;
      int urow = m0 + row; if (urow >= M) urow = M - 1;
      dma16(U + (size_t)urow * K + k0 + lchunk * 8, &Ut[(q * 32 + wave * 8) * 64]);
      dma16(Wt + (size_t)(n0 + row) * K + k0 + lchunk * 8, &Wl[(q * 32 + wave * 8) * 64]);
    }
    __syncthreads();   // drains vmcnt (global_load_lds) before LDS reads
#pragma unroll
    for (int s = 0; s < 2; ++s) {
      bf16x8 a[4], b[4];
#pragma unroll
      for (int mt = 0; mt < 4; ++mt)
        a[mt] = *(const bf16x8*)(&Ut[(wm + mt * 16 + lr) * 64 + (((s * 4 + lq) ^ (lr & 7)) << 3)]);
#pragma unroll
      for (int nt = 0; nt < 4; ++nt)
        b[nt] = *(const bf16x8*)(&Wl[(wn + nt * 16 + lr) * 64 + (((s * 4 + lq) ^ (lr & 7)) << 3)]);
#pragma unroll
      for (int mt = 0; mt < 4; ++mt)
#pragma unroll
        for (int nt = 0; nt < 4; ++nt)
          acc[mt][nt] = __builtin_amdgcn_mfma_f32_16x16x32_bf16(
              a[mt], b[nt], acc[mt][nt], 0, 0, 0);
    }
    __syncthreads();
  }

#pragma unroll
  for (int mt = 0; mt < 4; ++mt)
#pragma unroll
    for (int nt = 0; nt < 4; ++nt) {
      int col = n0 + wn + nt * 16 + lr;
      float bcol = bias[col];
#pragma unroll
      for (int r = 0; r < 4; ++r) {
        int row = m0 + wm + mt * 16 + lq * 4 + r;
        if (row < M) {
          float vv = acc[mt][nt][r] + bcol;
          if (RELU) vv = vv > 0.f ? vv : 0.f;
          if (OUTF32) ((float*)Out)[(size_t)row * Nc + col] = vv;
          else        ((bf16_t*)Out)[(size_t)row * Nc + col] = (bf16_t)vv;
        }
      }
    }
}

// ---------------- fused GINE gather with MFMA edge-linear ----------------
__global__ __launch_bounds__(256) void gine_gather_mfma_kernel(
    const bf16_t* __restrict__ h, const bf16_t* __restrict__ eat16,
    const int* __restrict__ src_sorted, const int* __restrict__ offs,
    const bf16_t* __restrict__ ewt, const float* __restrict__ eb,
    const float* __restrict__ eps_p, bf16_t* __restrict__ u) {
  constexpr int HP = H + 8;         // padded stride: rows offset 4 banks
  __shared__ bf16_t slin[16 * HP];  // 8448 B
  const int t = threadIdx.x;
  const int wave = t >> 6;
  const int lane = t & 63;
  const int lr = lane & 15;
  const int lq = lane >> 4;
  const int lane4 = lane * 4;
  const int n0 = blockIdx.x * 4;
  const int nodeN = n0 + wave;

  bf16x8 bfrag[4];
#pragma unroll
  for (int nt = 0; nt < 4; ++nt) {
    bf16x8 bv = {};
    if (lq < 2)
      bv = *(const bf16x8*)(ewt + ((wave * 64 + nt * 16 + lr) << 4) + (lq << 3));
    bfrag[nt] = bv;
  }
  float ebv[4];
#pragma unroll
  for (int i = 0; i < 4; ++i) ebv[i] = eb[lane4 + i];

  int bs = offs[n0], be = offs[n0 + 4];
  bs = clampi(bs, 0, N_EDGES);
  be = clampi(be, bs, N_EDGES);
  int ns = offs[nodeN], ne = offs[nodeN + 1];
  ns = clampi(ns, bs, be);
  ne = clampi(ne, ns, be);

  float acc[4] = {0.f, 0.f, 0.f, 0.f};

  for (int cb = bs; cb < be; cb += 16) {
    int arow = cb + lr;
    if (arow >= N_EDGES) arow = N_EDGES - 1;
    bf16x8 afrag = {};
    if (lq < 2)
      afrag = *(const bf16x8*)(eat16 + ((size_t)arow << 4) + (lq << 3));
    f32x4 c[4];
#pragma unroll
    for (int nt = 0; nt < 4; ++nt) {
      f32x4 z = {};
      c[nt] = __builtin_amdgcn_mfma_f32_16x16x32_bf16(afrag, bfrag[nt], z, 0, 0, 0);
    }
    __syncthreads();
#pragma unroll
    for (int nt = 0; nt < 4; ++nt)
#pragma unroll
      for (int r = 0; r < 4; ++r)
        slin[(lq * 4 + r) * HP + wave * 64 + nt * 16 + lr] = (bf16_t)c[nt][r];
    __syncthreads();
    int j0 = ns > cb ? ns : cb;
    int j1 = ne < cb + 16 ? ne : cb + 16;
    for (int j = j0; j < j1; ++j) {
      int s = src_sorted[j];
      bf16x4 hv = *(const bf16x4*)(h + (size_t)s * H + lane4);
      bf16x4 lv = *(const bf16x4*)(&slin[(j - cb) * HP + lane4]);
#pragma unroll
      for (int i = 0; i < 4; ++i)
        acc[i] += fmaxf((float)hv[i] + (float)lv[i] + ebv[i], 0.f);
    }
  }

  const float sc = 1.0f + eps_p[0];
  bf16x4 hs = *(const bf16x4*)(h + (size_t)nodeN * H + lane4);
  union { bf16x4 v; uint2 b; } o;
#pragma unroll
  for (int i = 0; i < 4; ++i) o.v[i] = (bf16_t)(sc * (float)hs[i] + acc[i]);
  *(uint2*)(u + (size_t)nodeN * H + lane4) = o.b;
}

// ------- GraphNorm (+relu, + optional fused mean-pool), 1 wave/graph ------
__global__ __launch_bounds__(64) void graphnorm_kernel(
    const bf16_t* __restrict__ v, bf16_t* __restrict__ hout,
    const int* __restrict__ starts,
    const float* __restrict__ w, const float* __restrict__ b,
    const float* __restrict__ ms, float* __restrict__ hg) {
  const int g = blockIdx.x;
  const int c0 = threadIdx.x * 4;
  int s = starts[g], e = starts[g + 1];
  s = clampi(s, 0, N_NODES);
  e = clampi(e, s, N_NODES);
  const float cnt = (float)((e - s) > 1 ? (e - s) : 1);
  float sx[4] = {0.f, 0.f, 0.f, 0.f}, sxx[4] = {0.f, 0.f, 0.f, 0.f};
  for (int i = s; i < e; ++i) {
    bf16x4 xv = *(const bf16x4*)(v + (size_t)i * H + c0);
#pragma unroll
    for (int j = 0; j < 4; ++j) { float f = (float)xv[j]; sx[j] += f; sxx[j] += f * f; }
  }
  float sub[4], inv[4], bb[4], psum[4] = {0.f, 0.f, 0.f, 0.f};
#pragma unroll
  for (int j = 0; j < 4; ++j) {
    float mean = sx[j] / cnt;
    sub[j] = ms[c0 + j] * mean;
    float var = sxx[j] / cnt - 2.f * sub[j] * mean + sub[j] * sub[j];
    var = fmaxf(var, 0.f);
    inv[j] = rsqrtf(var + 1e-5f) * w[c0 + j];
    bb[j] = b[c0 + j];
  }
  for (int i = s; i < e; ++i) {
    bf16x4 xv = *(const bf16x4*)(v + (size_t)i * H + c0);
    union { bf16x4 o; uint2 u; } pk;
#pragma unroll
    for (int j = 0; j < 4; ++j) {
      float o = ((float)xv[j] - sub[j]) * inv[j] + bb[j];
      o = o > 0.f ? o : 0.f;
      psum[j] += o;
      pk.o[j] = (bf16_t)o;
    }
    *(uint2*)(hout + (size_t)i * H + c0) = pk.u;
  }
  if (hg) {
#pragma unroll
    for (int j = 0; j < 4; ++j) hg[(size_t)g * H + c0 + j] = psum[j] / cnt;
  }
}

// ---- tiny tail heads (Nc=1 / Nc=8): Out[M x Nc] = In(bf16) @ W + b -------
__global__ void head_out_kernel(const bf16_t* __restrict__ In, const float* __restrict__ W,
                                const float* __restrict__ bias, float* __restrict__ Out,
                                int M, int K, int Nc) {
  int idx = blockIdx.x * blockDim.x + threadIdx.x;
  if (idx >= M * Nc) return;
  int r = idx / Nc, n = idx - r * Nc;
  float acc = bias[n];
  const bf16_t* in = In + (size_t)r * K;
  for (int k = 0; k < K; ++k) acc += (float)in[k] * W[(size_t)k * Nc + n];
  Out[idx] = acc;
}

extern "C" void kernel_launch(void* const* d_in, const int* in_sizes, int n_in,
                              void* d_out, int out_size, void* d_ws, size_t ws_size,
                              hipStream_t stream) {
  (void)in_sizes; (void)n_in; (void)out_size; (void)ws_size;
  const float* x        = (const float*)d_in[0];
  const int*   eidx     = (const int*)d_in[1];
  const float* eattr    = (const float*)d_in[2];
  const int*   batch    = (const int*)d_in[3];
  const float* node_W   = (const float*)d_in[4];
  const float* node_b   = (const float*)d_in[5];
  const float* conv_eps = (const float*)d_in[6];
  const float* edge_W   = (const float*)d_in[7];
  const float* edge_b   = (const float*)d_in[8];
  const float* mlp_W1   = (const float*)d_in[9];
  const float* mlp_b1   = (const float*)d_in[10];
  const float* mlp_W2   = (const float*)d_in[11];
  const float* mlp_b2   = (const float*)d_in[12];
  const float* gn_w     = (const float*)d_in[13];
  const float* gn_b     = (const float*)d_in[14];
  const float* gn_ms    = (const float*)d_in[15];
  const float* finv_W1  = (const float*)d_in[16];
  const float* finv_b1  = (const float*)d_in[17];
  const float* finv_W2  = (const float*)d_in[18];
  const float* finv_b2  = (const float*)d_in[19];
  const float* fspu_W1  = (const float*)d_in[20];
  const float* fspu_b1  = (const float*)d_in[21];
  const float* fspu_W2  = (const float*)d_in[22];
  const float* fspu_b2  = (const float*)d_in[23];
  const float* pred_W1  = (const float*)d_in[24];
  const float* pred_b1  = (const float*)d_in[25];
  const float* pred_W2  = (const float*)d_in[26];
  const float* pred_b2  = (const float*)d_in[27];
  const float* adv_W1   = (const float*)d_in[28];
  const float* adv_b1   = (const float*)d_in[29];
  const float* adv_W2   = (const float*)d_in[30];
  const float* adv_b2   = (const float*)d_in[31];
  float* out = (float*)d_out;

  float* out_hg = out;                                  // [G,H]
  float* out_zi = out + (size_t)N_GRAPH * H;            // [G,ZI]
  float* out_zs = out_zi + (size_t)N_GRAPH * ZIC;       // [G,ZS]
  float* out_yh = out_zs + (size_t)N_GRAPH * ZIC;       // [G]
  float* out_ev = out_yh + N_GRAPH;                     // [G,NE]

  // workspace carve-up (~119 MiB total)
  char* wp = (char*)d_ws;
  auto alloc = [&](size_t bytes) { char* p = wp; wp += (bytes + 255) & ~(size_t)255; return p; };
  bf16_t* A        = (bf16_t*)alloc((size_t)N_NODES * H * 2);   // h / t
  bf16_t* B        = (bf16_t*)alloc((size_t)N_NODES * H * 2);   // u / v
  bf16_t* Wt       = (bf16_t*)alloc((size_t)(H * ND + 6 * H * H) * 2);
  bf16_t* WtH      = (bf16_t*)alloc((size_t)(2 * ZIC * H + 4 * ZIC * ZIC) * 2);
  bf16_t* ewt16    = (bf16_t*)alloc((size_t)3 * 256 * 16 * 2);
  bf16_t* eat16    = (bf16_t*)alloc((size_t)N_EDGES * 16 * 2);
  int*    starts   = (int*)alloc((size_t)(N_GRAPH + 1) * 4);
  int*    counts   = (int*)alloc((size_t)N_NODES * 4);
  int*    cursor   = (int*)alloc((size_t)N_NODES * 4);
  int*    offs     = (int*)alloc((size_t)(N_NODES + 1) * 4);
  int*    bsum     = (int*)alloc((size_t)SCAN_B * 4);
  int*    perm     = (int*)alloc((size_t)N_EDGES * 4);
  int*    src_srt  = (int*)alloc((size_t)N_EDGES * 4);
  bf16_t* tmp1     = (bf16_t*)alloc((size_t)N_GRAPH * ZIC * 2);
  bf16_t* tmp2     = (bf16_t*)alloc((size_t)N_GRAPH * ZIC * 2);

  const int* srcp = eidx;
  const int* dstp = eidx + N_EDGES;
  const int nscan = (N_NODES + SCAN_B - 1) / SCAN_B;

  compute_starts_kernel<<<(N_NODES + 255) / 256, 256, 0, stream>>>(batch, starts, N_NODES, N_GRAPH);

  zero2_kernel<<<(N_NODES + 255) / 256, 256, 0, stream>>>(counts, cursor, N_NODES);
  count_deg_kernel<<<(N_EDGES + 255) / 256, 256, 0, stream>>>(dstp, counts, N_EDGES, N_NODES);
  scan1_kernel<<<nscan, SCAN_B, 0, stream>>>(counts, offs, bsum, N_NODES);
  scan2_kernel<<<1, 64, 0, stream>>>(bsum, nscan);
  scan3_kernel<<<nscan, SCAN_B, 0, stream>>>(offs, bsum, N_NODES);
  fill_perm_kernel<<<(N_EDGES + 255) / 256, 256, 0, stream>>>(dstp, offs, cursor, perm, N_EDGES, N_NODES);
  sort_src_kernel<<<(N_EDGES + 255) / 256, 256, 0, stream>>>(perm, srcp, src_srt, N_EDGES);
  build_eattr16_kernel<<<(N_EDGES * 16 + 255) / 256, 256, 0, stream>>>(eattr, perm, eat16, N_EDGES);
  build_ewt16_kernel<<<(3 * 256 * 16 + 255) / 256, 256, 0, stream>>>(edge_W, ewt16);

  bf16_t* WtN = Wt;
  auto Wt1l = [&](int l) { return Wt + H * ND + (size_t)(2 * l) * H * H; };
  auto Wt2l = [&](int l) { return Wt + H * ND + (size_t)(2 * l + 1) * H * H; };
  transpose_kernel<<<dim3(H / 32, ND / 32), dim3(32, 8), 0, stream>>>(node_W, WtN, ND, H);
  for (int l = 0; l < 3; ++l) {
    transpose_kernel<<<dim3(H / 32, H / 32), dim3(32, 8), 0, stream>>>(mlp_W1 + (size_t)l * H * H, Wt1l(l), H, H);
    transpose_kernel<<<dim3(H / 32, H / 32), dim3(32, 8), 0, stream>>>(mlp_W2 + (size_t)l * H * H, Wt2l(l), H, H);
  }
  bf16_t* fT1 = WtH;                          // [128 x 256]
  bf16_t* fT2 = fT1 + ZIC * H;                // [128 x 128]
  bf16_t* sT1 = fT2 + ZIC * ZIC;              // [128 x 256]
  bf16_t* sT2 = sT1 + ZIC * H;                // [128 x 128]
  bf16_t* pT1 = sT2 + ZIC * ZIC;              // [128 x 128]
  bf16_t* aT1 = pT1 + ZIC * ZIC;              // [128 x 128]
  transpose_kernel<<<dim3(ZIC / 32, H / 32), dim3(32, 8), 0, stream>>>(finv_W1, fT1, H, ZIC);
  transpose_kernel<<<dim3(ZIC / 32, ZIC / 32), dim3(32, 8), 0, stream>>>(finv_W2, fT2, ZIC, ZIC);
  transpose_kernel<<<dim3(ZIC / 32, H / 32), dim3(32, 8), 0, stream>>>(fspu_W1, sT1, H, ZIC);
  transpose_kernel<<<dim3(ZIC / 32, ZIC / 32), dim3(32, 8), 0, stream>>>(fspu_W2, sT2, ZIC, ZIC);
  transpose_kernel<<<dim3(ZIC / 32, ZIC / 32), dim3(32, 8), 0, stream>>>(pred_W1, pT1, ZIC, ZIC);
  transpose_kernel<<<dim3(ZIC / 32, ZIC / 32), dim3(32, 8), 0, stream>>>(adv_W1, aT1, ZIC, ZIC);

  dim3 ggrid((N_NODES + 127) / 128, H / 128);
  // h = x @ node_W + node_b (fp32 input -> VGPR-staging kernel)
  gemm128_kernel<ND, false, false><<<ggrid, 256, 0, stream>>>(x, WtN, node_b, A, N_NODES, H);

  for (int l = 0; l < 3; ++l) {
    gine_gather_mfma_kernel<<<N_NODES / 4, 256, 0, stream>>>(
        A, eat16, src_srt, offs, ewt16 + (size_t)l * 256 * 16,
        edge_b + l * H, conv_eps + l, B);
    gemm128_dma_kernel<H, true,  false><<<ggrid, 256, 0, stream>>>(B, Wt1l(l), mlp_b1 + l * H, A, N_NODES, H);
    gemm128_dma_kernel<H, false, false><<<ggrid, 256, 0, stream>>>(A, Wt2l(l), mlp_b2 + l * H, B, N_NODES, H);
    graphnorm_kernel<<<N_GRAPH, 64, 0, stream>>>(B, A, starts, gn_w + l * H, gn_b + l * H,
                                                 gn_ms + l * H, (l == 2) ? out_hg : nullptr);
  }

  // heads: layer1 (fp32 input) via VGPR kernel; layer2 (bf16 input) via DMA
  dim3 hgrid(N_GRAPH / 128, 1);
  gemm128_kernel<H,   true,  false, float><<<hgrid, 256, 0, stream>>>(out_hg, fT1, finv_b1, tmp1, N_GRAPH, ZIC);
  gemm128_dma_kernel<ZIC, false, true ><<<hgrid, 256, 0, stream>>>(tmp1, fT2, finv_b2, out_zi, N_GRAPH, ZIC);
  gemm128_kernel<H,   true,  false, float><<<hgrid, 256, 0, stream>>>(out_hg, sT1, fspu_b1, tmp2, N_GRAPH, ZIC);
  gemm128_dma_kernel<ZIC, false, true ><<<hgrid, 256, 0, stream>>>(tmp2, sT2, fspu_b2, out_zs, N_GRAPH, ZIC);
  gemm128_kernel<ZIC, true,  false, float><<<hgrid, 256, 0, stream>>>(out_zi, pT1, pred_b1, tmp1, N_GRAPH, ZIC);
  gemm128_kernel<ZIC, true,  false, float><<<hgrid, 256, 0, stream>>>(out_zi, aT1, adv_b1, tmp2, N_GRAPH, ZIC);
  head_out_kernel<<<(N_GRAPH + 255) / 256, 256, 0, stream>>>(tmp1, pred_W2, pred_b2, out_yh, N_GRAPH, ZIC, 1);
  head_out_kernel<<<(N_GRAPH * NE + 255) / 256, 256, 0, stream>>>(tmp2, adv_W2, adv_b2, out_ev, N_GRAPH, ZIC, NE);
}

// Round 9
// 854.677 us; speedup vs baseline: 1.9490x; 1.0914x over previous
//
#include <hip/hip_runtime.h>
#include <hip/hip_bf16.h>

typedef __bf16 bf16_t;
typedef __bf16 bf16x8 __attribute__((ext_vector_type(8)));
typedef __bf16 bf16x4 __attribute__((ext_vector_type(4)));
typedef float  f32x4  __attribute__((ext_vector_type(4)));

static constexpr int N_NODES = 100000;
static constexpr int N_EDGES = 300000;
static constexpr int N_GRAPH = 4096;
static constexpr int H  = 256;
static constexpr int ND = 64;
static constexpr int ZIC = 128;
static constexpr int NE = 8;
static constexpr int SCAN_B = 1024;

__device__ __forceinline__ int clampi(int v, int lo, int hi) {
  return v < lo ? lo : (v > hi ? hi : v);
}

// async 16B global -> LDS (wave-uniform LDS base + lane*16)
__device__ __forceinline__ void dma16(const bf16_t* g, bf16_t* lds_base) {
  __builtin_amdgcn_global_load_lds(
      (const __attribute__((address_space(1))) void*)g,
      (__attribute__((address_space(3))) void*)lds_base, 16, 0, 0);
}

// ---------------- graph segment starts (batch is sorted) ----------------
__global__ void compute_starts_kernel(const int* __restrict__ batch,
                                      int* __restrict__ starts, int N, int G) {
  int i = blockIdx.x * blockDim.x + threadIdx.x;
  if (i >= N) return;
  int b = clampi(batch[i], 0, G - 1);
  if (i == 0) {
    for (int g = 0; g <= b; ++g) starts[g] = 0;
  } else {
    int p = clampi(batch[i - 1], 0, G - 1);
    for (int g = p + 1; g <= b; ++g) starts[g] = i;
  }
  if (i == N - 1) {
    for (int g = b + 1; g <= G; ++g) starts[g] = N;
  }
}

// ---------------- CSR build ----------------
__global__ void zero2_kernel(int* __restrict__ a, int* __restrict__ b, int N) {
  int i = blockIdx.x * blockDim.x + threadIdx.x;
  if (i < N) { a[i] = 0; b[i] = 0; }
}

__global__ void count_deg_kernel(const int* __restrict__ dst, int* __restrict__ counts, int E, int N) {
  int e = blockIdx.x * blockDim.x + threadIdx.x;
  if (e < E) atomicAdd(&counts[clampi(dst[e], 0, N - 1)], 1);
}

__global__ __launch_bounds__(SCAN_B) void scan1_kernel(const int* __restrict__ counts,
                                                       int* __restrict__ offs,
                                                       int* __restrict__ bsum, int N) {
  __shared__ int tmp[SCAN_B];
  int i = blockIdx.x * SCAN_B + threadIdx.x;
  int v = (i < N) ? counts[i] : 0;
  tmp[threadIdx.x] = v;
  __syncthreads();
  for (int d = 1; d < SCAN_B; d <<= 1) {
    int t = (threadIdx.x >= d) ? tmp[threadIdx.x - d] : 0;
    __syncthreads();
    tmp[threadIdx.x] += t;
    __syncthreads();
  }
  if (i < N) offs[i + 1] = tmp[threadIdx.x];
  if (threadIdx.x == SCAN_B - 1) bsum[blockIdx.x] = tmp[SCAN_B - 1];
  if (i == 0) offs[0] = 0;
}

__global__ void scan2_kernel(int* __restrict__ bsum, int nblk) {
  if (blockIdx.x == 0 && threadIdx.x == 0) {
    int run = 0;
    for (int b = 0; b < nblk; ++b) { int v = bsum[b]; bsum[b] = run; run += v; }
  }
}

__global__ __launch_bounds__(SCAN_B) void scan3_kernel(int* __restrict__ offs,
                                                       const int* __restrict__ bsum, int N) {
  int i = blockIdx.x * SCAN_B + threadIdx.x;
  if (i < N) offs[i + 1] += bsum[blockIdx.x];
}

__global__ void fill_perm_kernel(const int* __restrict__ dst, const int* __restrict__ offs,
                                 int* __restrict__ cursor, int* __restrict__ perm, int E, int N) {
  int e = blockIdx.x * blockDim.x + threadIdx.x;
  if (e >= E) return;
  int d = clampi(dst[e], 0, N - 1);
  int pos = offs[d] + atomicAdd(&cursor[d], 1);
  if ((unsigned)pos < (unsigned)E) perm[pos] = e;
}

__global__ void sort_src_kernel(const int* __restrict__ perm, const int* __restrict__ src,
                                int* __restrict__ src_sorted, int E) {
  int p = blockIdx.x * blockDim.x + threadIdx.x;
  if (p >= E) return;
  int e = perm[p];
  e = ((unsigned)e < (unsigned)E) ? e : 0;
  int s = src[e];
  src_sorted[p] = ((unsigned)s < (unsigned)N_NODES) ? s : 0;
}

// eattr gathered to dst-sorted order, bf16, 16 per row
__global__ void build_eattr16_kernel(const float* __restrict__ eattr,
                                     const int* __restrict__ perm,
                                     bf16_t* __restrict__ ep, int E) {
  int idx = blockIdx.x * blockDim.x + threadIdx.x;
  if (idx >= E * 16) return;
  int p = idx >> 4, k = idx & 15;
  int e = perm[p];
  e = ((unsigned)e < (unsigned)E) ? e : 0;
  ep[idx] = (bf16_t)eattr[(size_t)e * 16 + k];
}

// edge_W[l] (16 x 256) -> eWt[l] (256 rows x 16 cols), bf16
__global__ void build_ewt16_kernel(const float* __restrict__ edge_W,
                                   bf16_t* __restrict__ ewt) {
  int idx = blockIdx.x * blockDim.x + threadIdx.x;
  if (idx >= 3 * 256 * 16) return;
  int l = idx / (256 * 16);
  int rem = idx - l * 256 * 16;
  int n = rem >> 4, k = rem & 15;
  ewt[idx] = (bf16_t)edge_W[(size_t)l * 16 * 256 + k * 256 + n];
}

// -------- fp32 transpose + bf16 cast: W[K x Nc] -> Wt[Nc x K] (bf16) ------
__global__ void transpose_kernel(const float* __restrict__ W,
                                 bf16_t* __restrict__ Wt, int K, int Nc) {
  __shared__ float tile[32][33];
  int n0 = blockIdx.x * 32, k0 = blockIdx.y * 32;
  int tx = threadIdx.x, ty = threadIdx.y;
  for (int i = ty; i < 32; i += 8)
    tile[i][tx] = W[(size_t)(k0 + i) * Nc + n0 + tx];
  __syncthreads();
  for (int i = ty; i < 32; i += 8)
    Wt[(size_t)(n0 + i) * K + k0 + tx] = (bf16_t)tile[tx][i];
}

// ---- staging loaders: 8 contiguous elements -> 8 bf16 (16B) in LDS ----
__device__ __forceinline__ void load8_to_lds(const bf16_t* p, bool valid, uint4* dst) {
  uint4 v = make_uint4(0u, 0u, 0u, 0u);
  if (valid) v = *(const uint4*)p;
  *dst = v;
}
__device__ __forceinline__ void load8_to_lds(const float* p, bool valid, uint4* dst) {
  float4 f0 = make_float4(0.f, 0.f, 0.f, 0.f), f1 = f0;
  if (valid) { f0 = *(const float4*)p; f1 = *(const float4*)(p + 4); }
  union { bf16_t b[8]; uint4 u; } pk;
  pk.b[0] = (bf16_t)f0.x; pk.b[1] = (bf16_t)f0.y;
  pk.b[2] = (bf16_t)f0.z; pk.b[3] = (bf16_t)f0.w;
  pk.b[4] = (bf16_t)f1.x; pk.b[5] = (bf16_t)f1.y;
  pk.b[6] = (bf16_t)f1.z; pk.b[7] = (bf16_t)f1.w;
  *dst = pk.u;
}

// ---------------- MFMA GEMM 128x128 (VGPR staging; fp32 or bf16 in) ------
template<int K, bool RELU, bool OUTF32, typename TIN>
__global__ __launch_bounds__(256) void gemm128_kernel(
    const TIN* __restrict__ U, const bf16_t* __restrict__ Wt,
    const float* __restrict__ bias, void* __restrict__ Out, int M, int Nc) {
  constexpr int LDT = 72;
  __shared__ bf16_t Ut[128 * LDT];
  __shared__ bf16_t Wl[128 * LDT];
  const int m0 = blockIdx.x * 128;
  const int n0 = blockIdx.y * 128;
  const int t = threadIdx.x;
  const int lane = t & 63;
  const int wave = t >> 6;
  const int wm = (wave >> 1) * 64;
  const int wn = (wave & 1) * 64;
  const int srow = t >> 1;
  const int sk = (t & 1) * 32;
  const int lr = lane & 15;
  const int lq = lane >> 4;
  const bool aok = (m0 + srow) < M;
  f32x4 acc[4][4] = {};

  for (int k0 = 0; k0 < K; k0 += 64) {
    const TIN* up = U + (size_t)(m0 + srow) * K + k0 + sk;
    const bf16_t* wp = Wt + (size_t)(n0 + srow) * K + k0 + sk;
#pragma unroll
    for (int q = 0; q < 4; ++q) {
      load8_to_lds(up + q * 8, aok, (uint4*)&Ut[srow * LDT + sk + q * 8]);
      load8_to_lds(wp + q * 8, true, (uint4*)&Wl[srow * LDT + sk + q * 8]);
    }
    __syncthreads();
#pragma unroll
    for (int s = 0; s < 2; ++s) {
      bf16x8 a[4], b[4];
#pragma unroll
      for (int mt = 0; mt < 4; ++mt)
        a[mt] = *(const bf16x8*)(&Ut[(wm + mt * 16 + lr) * LDT + s * 32 + lq * 8]);
#pragma unroll
      for (int nt = 0; nt < 4; ++nt)
        b[nt] = *(const bf16x8*)(&Wl[(wn + nt * 16 + lr) * LDT + s * 32 + lq * 8]);
#pragma unroll
      for (int mt = 0; mt < 4; ++mt)
#pragma unroll
        for (int nt = 0; nt < 4; ++nt)
          acc[mt][nt] = __builtin_amdgcn_mfma_f32_16x16x32_bf16(
              a[mt], b[nt], acc[mt][nt], 0, 0, 0);
    }
    __syncthreads();
  }

#pragma unroll
  for (int mt = 0; mt < 4; ++mt)
#pragma unroll
    for (int nt = 0; nt < 4; ++nt) {
      int col = n0 + wn + nt * 16 + lr;
      float bcol = bias[col];
#pragma unroll
      for (int r = 0; r < 4; ++r) {
        int row = m0 + wm + mt * 16 + lq * 4 + r;
        if (row < M) {
          float vv = acc[mt][nt][r] + bcol;
          if (RELU) vv = vv > 0.f ? vv : 0.f;
          if (OUTF32) ((float*)Out)[(size_t)row * Nc + col] = vv;
          else        ((bf16_t*)Out)[(size_t)row * Nc + col] = (bf16_t)vv;
        }
      }
    }
}

// ---------------- MFMA GEMM 64x64, BK=64 (heads: better occupancy) -------
template<int K, bool RELU, bool OUTF32, typename TIN>
__global__ __launch_bounds__(256) void gemm64_kernel(
    const TIN* __restrict__ U, const bf16_t* __restrict__ Wt,
    const float* __restrict__ bias, void* __restrict__ Out, int M, int Nc) {
  constexpr int LDT = 72;
  __shared__ bf16_t Ut[64 * LDT];
  __shared__ bf16_t Wl[64 * LDT];
  const int m0 = blockIdx.x * 64;
  const int n0 = blockIdx.y * 64;
  const int t = threadIdx.x;
  const int lane = t & 63;
  const int wave = t >> 6;
  const int wm = (wave >> 1) * 32;
  const int wn = (wave & 1) * 32;
  const int srow = t >> 2;
  const int sk = (t & 3) * 8;
  const int lr = lane & 15;
  const int lq = lane >> 4;
  const bool aok = (m0 + srow) < M;
  f32x4 acc[2][2] = {};

  for (int k0 = 0; k0 < K; k0 += 64) {
    const TIN* up = U + (size_t)(m0 + srow) * K + k0 + sk;
    const bf16_t* wp = Wt + (size_t)(n0 + srow) * K + k0 + sk;
    load8_to_lds(up,      aok, (uint4*)&Ut[srow * LDT + sk]);
    load8_to_lds(up + 32, aok, (uint4*)&Ut[srow * LDT + sk + 32]);
    load8_to_lds(wp,      true, (uint4*)&Wl[srow * LDT + sk]);
    load8_to_lds(wp + 32, true, (uint4*)&Wl[srow * LDT + sk + 32]);
    __syncthreads();
#pragma unroll
    for (int s = 0; s < 2; ++s) {
      bf16x8 a[2], b[2];
#pragma unroll
      for (int mt = 0; mt < 2; ++mt)
        a[mt] = *(const bf16x8*)(&Ut[(wm + mt * 16 + lr) * LDT + s * 32 + lq * 8]);
#pragma unroll
      for (int nt = 0; nt < 2; ++nt)
        b[nt] = *(const bf16x8*)(&Wl[(wn + nt * 16 + lr) * LDT + s * 32 + lq * 8]);
#pragma unroll
      for (int mt = 0; mt < 2; ++mt)
#pragma unroll
        for (int nt = 0; nt < 2; ++nt)
          acc[mt][nt] = __builtin_amdgcn_mfma_f32_16x16x32_bf16(
              a[mt], b[nt], acc[mt][nt], 0, 0, 0);
    }
    __syncthreads();
  }

#pragma unroll
  for (int mt = 0; mt < 2; ++mt)
#pragma unroll
    for (int nt = 0; nt < 2; ++nt) {
      int col = n0 + wn + nt * 16 + lr;
      float bcol = bias[col];
#pragma unroll
      for (int r = 0; r < 4; ++r) {
        int row = m0 + wm + mt * 16 + lq * 4 + r;
        if (row < M) {
          float vv = acc[mt][nt][r] + bcol;
          if (RELU) vv = vv > 0.f ? vv : 0.f;
          if (OUTF32) ((float*)Out)[(size_t)row * Nc + col] = vv;
          else        ((bf16_t*)Out)[(size_t)row * Nc + col] = (bf16_t)vv;
        }
      }
    }
}

// ------- MFMA GEMM 128x128, bf16 input, global_load_lds + XOR swizzle -----
template<int K, bool RELU, bool OUTF32>
__global__ __launch_bounds__(256) void gemm128_dma_kernel(
    const bf16_t* __restrict__ U, const bf16_t* __restrict__ Wt,
    const float* __restrict__ bias, void* __restrict__ Out, int M, int Nc) {
  __shared__ bf16_t Ut[128 * 64];
  __shared__ bf16_t Wl[128 * 64];
  const int t = threadIdx.x;
  const int lane = t & 63;
  const int wave = t >> 6;
  const int m0 = blockIdx.x * 128;
  const int n0 = blockIdx.y * 128;
  const int wm = (wave >> 1) * 64;
  const int wn = (wave & 1) * 64;
  const int lr = lane & 15;
  const int lq = lane >> 4;
  const int subrow = wave * 8 + (lane >> 3);        // + q*32
  const int lchunk = (lane & 7) ^ (lane >> 3);      // logical chunk to fetch
  f32x4 acc[4][4] = {};

  for (int k0 = 0; k0 < K; k0 += 64) {
#pragma unroll
    for (int q = 0; q < 4; ++q) {
      const int row = q * 32 + subrow;
      int urow = m0 + row; if (urow >= M) urow = M - 1;
      dma16(U + (size_t)urow * K + k0 + lchunk * 8, &Ut[(q * 32 + wave * 8) * 64]);
      dma16(Wt + (size_t)(n0 + row) * K + k0 + lchunk * 8, &Wl[(q * 32 + wave * 8) * 64]);
    }
    __syncthreads();
#pragma unroll
    for (int s = 0; s < 2; ++s) {
      bf16x8 a[4], b[4];
#pragma unroll
      for (int mt = 0; mt < 4; ++mt)
        a[mt] = *(const bf16x8*)(&Ut[(wm + mt * 16 + lr) * 64 + (((s * 4 + lq) ^ (lr & 7)) << 3)]);
#pragma unroll
      for (int nt = 0; nt < 4; ++nt)
        b[nt] = *(const bf16x8*)(&Wl[(wn + nt * 16 + lr) * 64 + (((s * 4 + lq) ^ (lr & 7)) << 3)]);
#pragma unroll
      for (int mt = 0; mt < 4; ++mt)
#pragma unroll
        for (int nt = 0; nt < 4; ++nt)
          acc[mt][nt] = __builtin_amdgcn_mfma_f32_16x16x32_bf16(
              a[mt], b[nt], acc[mt][nt], 0, 0, 0);
    }
    __syncthreads();
  }

#pragma unroll
  for (int mt = 0; mt < 4; ++mt)
#pragma unroll
    for (int nt = 0; nt < 4; ++nt) {
      int col = n0 + wn + nt * 16 + lr;
      float bcol = bias[col];
#pragma unroll
      for (int r = 0; r < 4; ++r) {
        int row = m0 + wm + mt * 16 + lq * 4 + r;
        if (row < M) {
          float vv = acc[mt][nt][r] + bcol;
          if (RELU) vv = vv > 0.f ? vv : 0.f;
          if (OUTF32) ((float*)Out)[(size_t)row * Nc + col] = vv;
          else        ((bf16_t*)Out)[(size_t)row * Nc + col] = (bf16_t)vv;
        }
      }
    }
}

// ---------------- fused GINE gather with MFMA edge-linear (v4) -----------
// Double-buffered slin: ONE barrier per chunk. Chunk i writes buf[i&1];
// consumers of chunk i-1 read buf[(i-1)&1]; buf[i&1] reuse at i+2 is
// fenced by barrier i+1. Consume loop batches 4 h-loads in flight.
__global__ __launch_bounds__(256) void gine_gather_mfma_kernel(
    const bf16_t* __restrict__ h, const bf16_t* __restrict__ eat16,
    const int* __restrict__ src_sorted, const int* __restrict__ offs,
    const bf16_t* __restrict__ ewt, const float* __restrict__ eb,
    const float* __restrict__ eps_p, bf16_t* __restrict__ u) {
  constexpr int HP = H + 8;
  __shared__ bf16_t slin[2][16 * HP];  // 16.9 KB
  const int t = threadIdx.x;
  const int wave = t >> 6;
  const int lane = t & 63;
  const int lr = lane & 15;
  const int lq = lane >> 4;
  const int lane4 = lane * 4;
  const int n0 = blockIdx.x * 4;
  const int nodeN = n0 + wave;

  // issue self-h load early (used only at the end)
  bf16x4 hs = *(const bf16x4*)(h + (size_t)nodeN * H + lane4);

  bf16x8 bfrag[4];
#pragma unroll
  for (int nt = 0; nt < 4; ++nt) {
    bf16x8 bv = {};
    if (lq < 2)
      bv = *(const bf16x8*)(ewt + ((wave * 64 + nt * 16 + lr) << 4) + (lq << 3));
    bfrag[nt] = bv;
  }
  float ebv[4];
#pragma unroll
  for (int i = 0; i < 4; ++i) ebv[i] = eb[lane4 + i];

  int bs = offs[n0], be = offs[n0 + 4];
  bs = clampi(bs, 0, N_EDGES);
  be = clampi(be, bs, N_EDGES);
  int ns = offs[nodeN], ne = offs[nodeN + 1];
  ns = clampi(ns, bs, be);
  ne = clampi(ne, ns, be);

  float acc[4] = {0.f, 0.f, 0.f, 0.f};
  int parity = 0;

  for (int cb = bs; cb < be; cb += 16, parity ^= 1) {
    int arow = cb + lr;
    if (arow >= N_EDGES) arow = N_EDGES - 1;
    bf16x8 afrag = {};
    if (lq < 2)
      afrag = *(const bf16x8*)(eat16 + ((size_t)arow << 4) + (lq << 3));
    f32x4 c[4];
#pragma unroll
    for (int nt = 0; nt < 4; ++nt) {
      f32x4 z = {};
      c[nt] = __builtin_amdgcn_mfma_f32_16x16x32_bf16(afrag, bfrag[nt], z, 0, 0, 0);
    }
#pragma unroll
    for (int nt = 0; nt < 4; ++nt)
#pragma unroll
      for (int r = 0; r < 4; ++r)
        slin[parity][(lq * 4 + r) * HP + wave * 64 + nt * 16 + lr] = (bf16_t)c[nt][r];
    __syncthreads();
    // consume this wave's node's edges within [cb, cb+16), 4 loads in flight
    int j0 = ns > cb ? ns : cb;
    int j1 = ne < cb + 16 ? ne : cb + 16;
    for (int jb = j0; jb < j1; jb += 4) {
      int sidx[4];
#pragma unroll
      for (int q = 0; q < 4; ++q) {
        int jj = jb + q; if (jj > j1 - 1) jj = j1 - 1;
        sidx[q] = src_sorted[jj];
      }
      bf16x4 hv[4];
#pragma unroll
      for (int q = 0; q < 4; ++q)
        hv[q] = *(const bf16x4*)(h + (size_t)sidx[q] * H + lane4);
#pragma unroll
      for (int q = 0; q < 4; ++q) {
        if (jb + q < j1) {
          bf16x4 lv = *(const bf16x4*)(&slin[parity][(jb + q - cb) * HP + lane4]);
#pragma unroll
          for (int i = 0; i < 4; ++i)
            acc[i] += fmaxf((float)hv[q][i] + (float)lv[i] + ebv[i], 0.f);
        }
      }
    }
  }

  const float sc = 1.0f + eps_p[0];
  union { bf16x4 v; uint2 b; } o;
#pragma unroll
  for (int i = 0; i < 4; ++i) o.v[i] = (bf16_t)(sc * (float)hs[i] + acc[i]);
  *(uint2*)(u + (size_t)nodeN * H + lane4) = o.b;
}

// ------- GraphNorm (+relu, + optional fused mean-pool), 1 wave/graph ------
__global__ __launch_bounds__(64) void graphnorm_kernel(
    const bf16_t* __restrict__ v, bf16_t* __restrict__ hout,
    const int* __restrict__ starts,
    const float* __restrict__ w, const float* __restrict__ b,
    const float* __restrict__ ms, float* __restrict__ hg) {
  const int g = blockIdx.x;
  const int c0 = threadIdx.x * 4;
  int s = starts[g], e = starts[g + 1];
  s = clampi(s, 0, N_NODES);
  e = clampi(e, s, N_NODES);
  const float cnt = (float)((e - s) > 1 ? (e - s) : 1);
  float sx[4] = {0.f, 0.f, 0.f, 0.f}, sxx[4] = {0.f, 0.f, 0.f, 0.f};
  for (int i = s; i < e; ++i) {
    bf16x4 xv = *(const bf16x4*)(v + (size_t)i * H + c0);
#pragma unroll
    for (int j = 0; j < 4; ++j) { float f = (float)xv[j]; sx[j] += f; sxx[j] += f * f; }
  }
  float sub[4], inv[4], bb[4], psum[4] = {0.f, 0.f, 0.f, 0.f};
#pragma unroll
  for (int j = 0; j < 4; ++j) {
    float mean = sx[j] / cnt;
    sub[j] = ms[c0 + j] * mean;
    float var = sxx[j] / cnt - 2.f * sub[j] * mean + sub[j] * sub[j];
    var = fmaxf(var, 0.f);
    inv[j] = rsqrtf(var + 1e-5f) * w[c0 + j];
    bb[j] = b[c0 + j];
  }
  for (int i = s; i < e; ++i) {
    bf16x4 xv = *(const bf16x4*)(v + (size_t)i * H + c0);
    union { bf16x4 o; uint2 u; } pk;
#pragma unroll
    for (int j = 0; j < 4; ++j) {
      float o = ((float)xv[j] - sub[j]) * inv[j] + bb[j];
      o = o > 0.f ? o : 0.f;
      psum[j] += o;
      pk.o[j] = (bf16_t)o;
    }
    *(uint2*)(hout + (size_t)i * H + c0) = pk.u;
  }
  if (hg) {
#pragma unroll
    for (int j = 0; j < 4; ++j) hg[(size_t)g * H + c0 + j] = psum[j] / cnt;
  }
}

// ---- tiny tail heads (Nc=1 / Nc=8): Out[M x Nc] = In(bf16) @ W + b -------
__global__ void head_out_kernel(const bf16_t* __restrict__ In, const float* __restrict__ W,
                                const float* __restrict__ bias, float* __restrict__ Out,
                                int M, int K, int Nc) {
  int idx = blockIdx.x * blockDim.x + threadIdx.x;
  if (idx >= M * Nc) return;
  int r = idx / Nc, n = idx - r * Nc;
  float acc = bias[n];
  const bf16_t* in = In + (size_t)r * K;
  for (int k = 0; k < K; ++k) acc += (float)in[k] * W[(size_t)k * Nc + n];
  Out[idx] = acc;
}

extern "C" void kernel_launch(void* const* d_in, const int* in_sizes, int n_in,
                              void* d_out, int out_size, void* d_ws, size_t ws_size,
                              hipStream_t stream) {
  (void)in_sizes; (void)n_in; (void)out_size; (void)ws_size;
  const float* x        = (const float*)d_in[0];
  const int*   eidx     = (const int*)d_in[1];
  const float* eattr    = (const float*)d_in[2];
  const int*   batch    = (const int*)d_in[3];
  const float* node_W   = (const float*)d_in[4];
  const float* node_b   = (const float*)d_in[5];
  const float* conv_eps = (const float*)d_in[6];
  const float* edge_W   = (const float*)d_in[7];
  const float* edge_b   = (const float*)d_in[8];
  const float* mlp_W1   = (const float*)d_in[9];
  const float* mlp_b1   = (const float*)d_in[10];
  const float* mlp_W2   = (const float*)d_in[11];
  const float* mlp_b2   = (const float*)d_in[12];
  const float* gn_w     = (const float*)d_in[13];
  const float* gn_b     = (const float*)d_in[14];
  const float* gn_ms    = (const float*)d_in[15];
  const float* finv_W1  = (const float*)d_in[16];
  const float* finv_b1  = (const float*)d_in[17];
  const float* finv_W2  = (const float*)d_in[18];
  const float* finv_b2  = (const float*)d_in[19];
  const float* fspu_W1  = (const float*)d_in[20];
  const float* fspu_b1  = (const float*)d_in[21];
  const float* fspu_W2  = (const float*)d_in[22];
  const float* fspu_b2  = (const float*)d_in[23];
  const float* pred_W1  = (const float*)d_in[24];
  const float* pred_b1  = (const float*)d_in[25];
  const float* pred_W2  = (const float*)d_in[26];
  const float* pred_b2  = (const float*)d_in[27];
  const float* adv_W1   = (const float*)d_in[28];
  const float* adv_b1   = (const float*)d_in[29];
  const float* adv_W2   = (const float*)d_in[30];
  const float* adv_b2   = (const float*)d_in[31];
  float* out = (float*)d_out;

  float* out_hg = out;                                  // [G,H]
  float* out_zi = out + (size_t)N_GRAPH * H;            // [G,ZI]
  float* out_zs = out_zi + (size_t)N_GRAPH * ZIC;       // [G,ZS]
  float* out_yh = out_zs + (size_t)N_GRAPH * ZIC;       // [G]
  float* out_ev = out_yh + N_GRAPH;                     // [G,NE]

  // workspace carve-up (~119 MiB total)
  char* wp = (char*)d_ws;
  auto alloc = [&](size_t bytes) { char* p = wp; wp += (bytes + 255) & ~(size_t)255; return p; };
  bf16_t* A        = (bf16_t*)alloc((size_t)N_NODES * H * 2);   // h / t
  bf16_t* B        = (bf16_t*)alloc((size_t)N_NODES * H * 2);   // u / v
  bf16_t* Wt       = (bf16_t*)alloc((size_t)(H * ND + 6 * H * H) * 2);
  bf16_t* WtH      = (bf16_t*)alloc((size_t)(2 * ZIC * H + 4 * ZIC * ZIC) * 2);
  bf16_t* ewt16    = (bf16_t*)alloc((size_t)3 * 256 * 16 * 2);
  bf16_t* eat16    = (bf16_t*)alloc((size_t)N_EDGES * 16 * 2);
  int*    starts   = (int*)alloc((size_t)(N_GRAPH + 1) * 4);
  int*    counts   = (int*)alloc((size_t)N_NODES * 4);
  int*    cursor   = (int*)alloc((size_t)N_NODES * 4);
  int*    offs     = (int*)alloc((size_t)(N_NODES + 1) * 4);
  int*    bsum     = (int*)alloc((size_t)SCAN_B * 4);
  int*    perm     = (int*)alloc((size_t)N_EDGES * 4);
  int*    src_srt  = (int*)alloc((size_t)N_EDGES * 4);
  bf16_t* tmp1     = (bf16_t*)alloc((size_t)N_GRAPH * ZIC * 2);
  bf16_t* tmp2     = (bf16_t*)alloc((size_t)N_GRAPH * ZIC * 2);

  const int* srcp = eidx;
  const int* dstp = eidx + N_EDGES;
  const int nscan = (N_NODES + SCAN_B - 1) / SCAN_B;

  compute_starts_kernel<<<(N_NODES + 255) / 256, 256, 0, stream>>>(batch, starts, N_NODES, N_GRAPH);

  zero2_kernel<<<(N_NODES + 255) / 256, 256, 0, stream>>>(counts, cursor, N_NODES);
  count_deg_kernel<<<(N_EDGES + 255) / 256, 256, 0, stream>>>(dstp, counts, N_EDGES, N_NODES);
  scan1_kernel<<<nscan, SCAN_B, 0, stream>>>(counts, offs, bsum, N_NODES);
  scan2_kernel<<<1, 64, 0, stream>>>(bsum, nscan);
  scan3_kernel<<<nscan, SCAN_B, 0, stream>>>(offs, bsum, N_NODES);
  fill_perm_kernel<<<(N_EDGES + 255) / 256, 256, 0, stream>>>(dstp, offs, cursor, perm, N_EDGES, N_NODES);
  sort_src_kernel<<<(N_EDGES + 255) / 256, 256, 0, stream>>>(perm, srcp, src_srt, N_EDGES);
  build_eattr16_kernel<<<(N_EDGES * 16 + 255) / 256, 256, 0, stream>>>(eattr, perm, eat16, N_EDGES);
  build_ewt16_kernel<<<(3 * 256 * 16 + 255) / 256, 256, 0, stream>>>(edge_W, ewt16);

  bf16_t* WtN = Wt;
  auto Wt1l = [&](int l) { return Wt + H * ND + (size_t)(2 * l) * H * H; };
  auto Wt2l = [&](int l) { return Wt + H * ND + (size_t)(2 * l + 1) * H * H; };
  transpose_kernel<<<dim3(H / 32, ND / 32), dim3(32, 8), 0, stream>>>(node_W, WtN, ND, H);
  for (int l = 0; l < 3; ++l) {
    transpose_kernel<<<dim3(H / 32, H / 32), dim3(32, 8), 0, stream>>>(mlp_W1 + (size_t)l * H * H, Wt1l(l), H, H);
    transpose_kernel<<<dim3(H / 32, H / 32), dim3(32, 8), 0, stream>>>(mlp_W2 + (size_t)l * H * H, Wt2l(l), H, H);
  }
  bf16_t* fT1 = WtH;                          // [128 x 256]
  bf16_t* fT2 = fT1 + ZIC * H;                // [128 x 128]
  bf16_t* sT1 = fT2 + ZIC * ZIC;              // [128 x 256]
  bf16_t* sT2 = sT1 + ZIC * H;                // [128 x 128]
  bf16_t* pT1 = sT2 + ZIC * ZIC;              // [128 x 128]
  bf16_t* aT1 = pT1 + ZIC * ZIC;              // [128 x 128]
  transpose_kernel<<<dim3(ZIC / 32, H / 32), dim3(32, 8), 0, stream>>>(finv_W1, fT1, H, ZIC);
  transpose_kernel<<<dim3(ZIC / 32, ZIC / 32), dim3(32, 8), 0, stream>>>(finv_W2, fT2, ZIC, ZIC);
  transpose_kernel<<<dim3(ZIC / 32, H / 32), dim3(32, 8), 0, stream>>>(fspu_W1, sT1, H, ZIC);
  transpose_kernel<<<dim3(ZIC / 32, ZIC / 32), dim3(32, 8), 0, stream>>>(fspu_W2, sT2, ZIC, ZIC);
  transpose_kernel<<<dim3(ZIC / 32, ZIC / 32), dim3(32, 8), 0, stream>>>(pred_W1, pT1, ZIC, ZIC);
  transpose_kernel<<<dim3(ZIC / 32, ZIC / 32), dim3(32, 8), 0, stream>>>(adv_W1, aT1, ZIC, ZIC);

  dim3 ggrid((N_NODES + 127) / 128, H / 128);
  // h = x @ node_W + node_b (fp32 input -> VGPR-staging kernel)
  gemm128_kernel<ND, false, false><<<ggrid, 256, 0, stream>>>(x, WtN, node_b, A, N_NODES, H);

  for (int l = 0; l < 3; ++l) {
    gine_gather_mfma_kernel<<<N_NODES / 4, 256, 0, stream>>>(
        A, eat16, src_srt, offs, ewt16 + (size_t)l * 256 * 16,
        edge_b + l * H, conv_eps + l, B);
    gemm128_dma_kernel<H, true,  false><<<ggrid, 256, 0, stream>>>(B, Wt1l(l), mlp_b1 + l * H, A, N_NODES, H);
    gemm128_dma_kernel<H, false, false><<<ggrid, 256, 0, stream>>>(A, Wt2l(l), mlp_b2 + l * H, B, N_NODES, H);
    graphnorm_kernel<<<N_GRAPH, 64, 0, stream>>>(B, A, starts, gn_w + l * H, gn_b + l * H,
                                                 gn_ms + l * H, (l == 2) ? out_hg : nullptr);
  }

  // heads via 64x64-tile GEMM (M=4096 -> 128 blocks: better CU coverage)
  dim3 hgrid(N_GRAPH / 64, ZIC / 64);
  gemm64_kernel<H,   true,  false, float ><<<hgrid, 256, 0, stream>>>(out_hg, fT1, finv_b1, tmp1, N_GRAPH, ZIC);
  gemm64_kernel<ZIC, false, true,  bf16_t><<<hgrid, 256, 0, stream>>>(tmp1, fT2, finv_b2, out_zi, N_GRAPH, ZIC);
  gemm64_kernel<H,   true,  false, float ><<<hgrid, 256, 0, stream>>>(out_hg, sT1, fspu_b1, tmp2, N_GRAPH, ZIC);
  gemm64_kernel<ZIC, false, true,  bf16_t><<<hgrid, 256, 0, stream>>>(tmp2, sT2, fspu_b2, out_zs, N_GRAPH, ZIC);
  gemm64_kernel<ZIC, true,  false, float ><<<hgrid, 256, 0, stream>>>(out_zi, pT1, pred_b1, tmp1, N_GRAPH, ZIC);
  gemm64_kernel<ZIC, true,  false, float ><<<hgrid, 256, 0, stream>>>(out_zi, aT1, adv_b1, tmp2, N_GRAPH, ZIC);
  head_out_kernel<<<(N_GRAPH + 255) / 256, 256, 0, stream>>>(tmp1, pred_W2, pred_b2, out_yh, N_GRAPH, ZIC, 1);
  head_out_kernel<<<(N_GRAPH * NE + 255) / 256, 256, 0, stream>>>(tmp2, adv_W2, adv_b2, out_ev, N_GRAPH, ZIC, NE);
}

// Round 10
// 817.098 us; speedup vs baseline: 2.0386x; 1.0460x over previous
//
#include <hip/hip_runtime.h>
#include <hip/hip_bf16.h>

typedef __bf16 bf16_t;
typedef __bf16 bf16x8 __attribute__((ext_vector_type(8)));
typedef __bf16 bf16x4 __attribute__((ext_vector_type(4)));
typedef float  f32x4  __attribute__((ext_vector_type(4)));

static constexpr int N_NODES = 100000;
static constexpr int N_EDGES = 300000;
static constexpr int N_GRAPH = 4096;
static constexpr int H  = 256;
static constexpr int ND = 64;
static constexpr int ZIC = 128;
static constexpr int NE = 8;
static constexpr int SCAN_B = 1024;

__device__ __forceinline__ int clampi(int v, int lo, int hi) {
  return v < lo ? lo : (v > hi ? hi : v);
}

// async 16B global -> LDS (wave-uniform LDS base + lane*16)
__device__ __forceinline__ void dma16(const bf16_t* g, bf16_t* lds_base) {
  __builtin_amdgcn_global_load_lds(
      (const __attribute__((address_space(1))) void*)g,
      (__attribute__((address_space(3))) void*)lds_base, 16, 0, 0);
}

// ---------------- graph segment starts (batch is sorted) ----------------
__global__ void compute_starts_kernel(const int* __restrict__ batch,
                                      int* __restrict__ starts, int N, int G) {
  int i = blockIdx.x * blockDim.x + threadIdx.x;
  if (i >= N) return;
  int b = clampi(batch[i], 0, G - 1);
  if (i == 0) {
    for (int g = 0; g <= b; ++g) starts[g] = 0;
  } else {
    int p = clampi(batch[i - 1], 0, G - 1);
    for (int g = p + 1; g <= b; ++g) starts[g] = i;
  }
  if (i == N - 1) {
    for (int g = b + 1; g <= G; ++g) starts[g] = N;
  }
}

// ---------------- CSR build ----------------
__global__ void zero2_kernel(int* __restrict__ a, int* __restrict__ b, int N) {
  int i = blockIdx.x * blockDim.x + threadIdx.x;
  if (i < N) { a[i] = 0; b[i] = 0; }
}

__global__ void count_deg_kernel(const int* __restrict__ dst, int* __restrict__ counts, int E, int N) {
  int e = blockIdx.x * blockDim.x + threadIdx.x;
  if (e < E) atomicAdd(&counts[clampi(dst[e], 0, N - 1)], 1);
}

__global__ __launch_bounds__(SCAN_B) void scan1_kernel(const int* __restrict__ counts,
                                                       int* __restrict__ offs,
                                                       int* __restrict__ bsum, int N) {
  __shared__ int tmp[SCAN_B];
  int i = blockIdx.x * SCAN_B + threadIdx.x;
  int v = (i < N) ? counts[i] : 0;
  tmp[threadIdx.x] = v;
  __syncthreads();
  for (int d = 1; d < SCAN_B; d <<= 1) {
    int t = (threadIdx.x >= d) ? tmp[threadIdx.x - d] : 0;
    __syncthreads();
    tmp[threadIdx.x] += t;
    __syncthreads();
  }
  if (i < N) offs[i + 1] = tmp[threadIdx.x];
  if (threadIdx.x == SCAN_B - 1) bsum[blockIdx.x] = tmp[SCAN_B - 1];
  if (i == 0) offs[0] = 0;
}

__global__ void scan2_kernel(int* __restrict__ bsum, int nblk) {
  if (blockIdx.x == 0 && threadIdx.x == 0) {
    int run = 0;
    for (int b = 0; b < nblk; ++b) { int v = bsum[b]; bsum[b] = run; run += v; }
  }
}

__global__ __launch_bounds__(SCAN_B) void scan3_kernel(int* __restrict__ offs,
                                                       const int* __restrict__ bsum, int N) {
  int i = blockIdx.x * SCAN_B + threadIdx.x;
  if (i < N) offs[i + 1] += bsum[blockIdx.x];
}

// fused: compute position AND scatter src_sorted + eattr(bf16) in one pass
__global__ void fill_scatter_kernel(const int* __restrict__ src, const int* __restrict__ dst,
                                    const float* __restrict__ eattr,
                                    const int* __restrict__ offs, int* __restrict__ cursor,
                                    int* __restrict__ src_srt, bf16_t* __restrict__ eat16,
                                    int E, int N) {
  int e = blockIdx.x * blockDim.x + threadIdx.x;
  if (e >= E) return;
  int d = clampi(dst[e], 0, N - 1);
  int pos = offs[d] + atomicAdd(&cursor[d], 1);
  if ((unsigned)pos >= (unsigned)E) return;
  int s = src[e];
  src_srt[pos] = ((unsigned)s < (unsigned)N_NODES) ? s : 0;
  const float* ea = eattr + (size_t)e * 16;
  union { bf16_t b[16]; uint4 u[2]; } pk;
#pragma unroll
  for (int k = 0; k < 16; ++k) pk.b[k] = (bf16_t)ea[k];
  uint4* dst16 = (uint4*)(eat16 + ((size_t)pos << 4));
  dst16[0] = pk.u[0];
  dst16[1] = pk.u[1];
}

// edge_W[l] (16 x 256) -> eWt[l] (256 rows x 16 cols), bf16
__global__ void build_ewt16_kernel(const float* __restrict__ edge_W,
                                   bf16_t* __restrict__ ewt) {
  int idx = blockIdx.x * blockDim.x + threadIdx.x;
  if (idx >= 3 * 256 * 16) return;
  int l = idx / (256 * 16);
  int rem = idx - l * 256 * 16;
  int n = rem >> 4, k = rem & 15;
  ewt[idx] = (bf16_t)edge_W[(size_t)l * 16 * 256 + k * 256 + n];
}

// -------- fp32 transpose + bf16 cast: W[K x Nc] -> Wt[Nc x K] (bf16) ------
// batched over blockIdx.z with strides
__global__ void transpose_kernel(const float* __restrict__ W,
                                 bf16_t* __restrict__ Wt, int K, int Nc,
                                 size_t srcStride, size_t dstStride) {
  __shared__ float tile[32][33];
  const float* Wz = W + (size_t)blockIdx.z * srcStride;
  bf16_t* Wtz = Wt + (size_t)blockIdx.z * dstStride;
  int n0 = blockIdx.x * 32, k0 = blockIdx.y * 32;
  int tx = threadIdx.x, ty = threadIdx.y;
  for (int i = ty; i < 32; i += 8)
    tile[i][tx] = Wz[(size_t)(k0 + i) * Nc + n0 + tx];
  __syncthreads();
  for (int i = ty; i < 32; i += 8)
    Wtz[(size_t)(n0 + i) * K + k0 + tx] = (bf16_t)tile[tx][i];
}

// ---- staging loaders: 8 contiguous elements -> 8 bf16 (16B) in LDS ----
__device__ __forceinline__ void load8_to_lds(const bf16_t* p, bool valid, uint4* dst) {
  uint4 v = make_uint4(0u, 0u, 0u, 0u);
  if (valid) v = *(const uint4*)p;
  *dst = v;
}
__device__ __forceinline__ void load8_to_lds(const float* p, bool valid, uint4* dst) {
  float4 f0 = make_float4(0.f, 0.f, 0.f, 0.f), f1 = f0;
  if (valid) { f0 = *(const float4*)p; f1 = *(const float4*)(p + 4); }
  union { bf16_t b[8]; uint4 u; } pk;
  pk.b[0] = (bf16_t)f0.x; pk.b[1] = (bf16_t)f0.y;
  pk.b[2] = (bf16_t)f0.z; pk.b[3] = (bf16_t)f0.w;
  pk.b[4] = (bf16_t)f1.x; pk.b[5] = (bf16_t)f1.y;
  pk.b[6] = (bf16_t)f1.z; pk.b[7] = (bf16_t)f1.w;
  *dst = pk.u;
}

// ---------------- MFMA GEMM 128x128 (VGPR staging; fp32 or bf16 in) ------
template<int K, bool RELU, bool OUTF32, typename TIN>
__global__ __launch_bounds__(256) void gemm128_kernel(
    const TIN* __restrict__ U, const bf16_t* __restrict__ Wt,
    const float* __restrict__ bias, void* __restrict__ Out, int M, int Nc) {
  constexpr int LDT = 72;
  __shared__ bf16_t Ut[128 * LDT];
  __shared__ bf16_t Wl[128 * LDT];
  const int m0 = blockIdx.x * 128;
  const int n0 = blockIdx.y * 128;
  const int t = threadIdx.x;
  const int lane = t & 63;
  const int wave = t >> 6;
  const int wm = (wave >> 1) * 64;
  const int wn = (wave & 1) * 64;
  const int srow = t >> 1;
  const int sk = (t & 1) * 32;
  const int lr = lane & 15;
  const int lq = lane >> 4;
  const bool aok = (m0 + srow) < M;
  f32x4 acc[4][4] = {};

  for (int k0 = 0; k0 < K; k0 += 64) {
    const TIN* up = U + (size_t)(m0 + srow) * K + k0 + sk;
    const bf16_t* wp = Wt + (size_t)(n0 + srow) * K + k0 + sk;
#pragma unroll
    for (int q = 0; q < 4; ++q) {
      load8_to_lds(up + q * 8, aok, (uint4*)&Ut[srow * LDT + sk + q * 8]);
      load8_to_lds(wp + q * 8, true, (uint4*)&Wl[srow * LDT + sk + q * 8]);
    }
    __syncthreads();
#pragma unroll
    for (int s = 0; s < 2; ++s) {
      bf16x8 a[4], b[4];
#pragma unroll
      for (int mt = 0; mt < 4; ++mt)
        a[mt] = *(const bf16x8*)(&Ut[(wm + mt * 16 + lr) * LDT + s * 32 + lq * 8]);
#pragma unroll
      for (int nt = 0; nt < 4; ++nt)
        b[nt] = *(const bf16x8*)(&Wl[(wn + nt * 16 + lr) * LDT + s * 32 + lq * 8]);
#pragma unroll
      for (int mt = 0; mt < 4; ++mt)
#pragma unroll
        for (int nt = 0; nt < 4; ++nt)
          acc[mt][nt] = __builtin_amdgcn_mfma_f32_16x16x32_bf16(
              a[mt], b[nt], acc[mt][nt], 0, 0, 0);
    }
    __syncthreads();
  }

#pragma unroll
  for (int mt = 0; mt < 4; ++mt)
#pragma unroll
    for (int nt = 0; nt < 4; ++nt) {
      int col = n0 + wn + nt * 16 + lr;
      float bcol = bias[col];
#pragma unroll
      for (int r = 0; r < 4; ++r) {
        int row = m0 + wm + mt * 16 + lq * 4 + r;
        if (row < M) {
          float vv = acc[mt][nt][r] + bcol;
          if (RELU) vv = vv > 0.f ? vv : 0.f;
          if (OUTF32) ((float*)Out)[(size_t)row * Nc + col] = vv;
          else        ((bf16_t*)Out)[(size_t)row * Nc + col] = (bf16_t)vv;
        }
      }
    }
}

// ---------------- MFMA GEMM 64x64, BK=64 (heads: better occupancy) -------
template<int K, bool RELU, bool OUTF32, typename TIN>
__global__ __launch_bounds__(256) void gemm64_kernel(
    const TIN* __restrict__ U, const bf16_t* __restrict__ Wt,
    const float* __restrict__ bias, void* __restrict__ Out, int M, int Nc) {
  constexpr int LDT = 72;
  __shared__ bf16_t Ut[64 * LDT];
  __shared__ bf16_t Wl[64 * LDT];
  const int m0 = blockIdx.x * 64;
  const int n0 = blockIdx.y * 64;
  const int t = threadIdx.x;
  const int lane = t & 63;
  const int wave = t >> 6;
  const int wm = (wave >> 1) * 32;
  const int wn = (wave & 1) * 32;
  const int srow = t >> 2;
  const int sk = (t & 3) * 8;
  const int lr = lane & 15;
  const int lq = lane >> 4;
  const bool aok = (m0 + srow) < M;
  f32x4 acc[2][2] = {};

  for (int k0 = 0; k0 < K; k0 += 64) {
    const TIN* up = U + (size_t)(m0 + srow) * K + k0 + sk;
    const bf16_t* wp = Wt + (size_t)(n0 + srow) * K + k0 + sk;
    load8_to_lds(up,      aok, (uint4*)&Ut[srow * LDT + sk]);
    load8_to_lds(up + 32, aok, (uint4*)&Ut[srow * LDT + sk + 32]);
    load8_to_lds(wp,      true, (uint4*)&Wl[srow * LDT + sk]);
    load8_to_lds(wp + 32, true, (uint4*)&Wl[srow * LDT + sk + 32]);
    __syncthreads();
#pragma unroll
    for (int s = 0; s < 2; ++s) {
      bf16x8 a[2], b[2];
#pragma unroll
      for (int mt = 0; mt < 2; ++mt)
        a[mt] = *(const bf16x8*)(&Ut[(wm + mt * 16 + lr) * LDT + s * 32 + lq * 8]);
#pragma unroll
      for (int nt = 0; nt < 2; ++nt)
        b[nt] = *(const bf16x8*)(&Wl[(wn + nt * 16 + lr) * LDT + s * 32 + lq * 8]);
#pragma unroll
      for (int mt = 0; mt < 2; ++mt)
#pragma unroll
        for (int nt = 0; nt < 2; ++nt)
          acc[mt][nt] = __builtin_amdgcn_mfma_f32_16x16x32_bf16(
              a[mt], b[nt], acc[mt][nt], 0, 0, 0);
    }
    __syncthreads();
  }

#pragma unroll
  for (int mt = 0; mt < 2; ++mt)
#pragma unroll
    for (int nt = 0; nt < 2; ++nt) {
      int col = n0 + wn + nt * 16 + lr;
      float bcol = bias[col];
#pragma unroll
      for (int r = 0; r < 4; ++r) {
        int row = m0 + wm + mt * 16 + lq * 4 + r;
        if (row < M) {
          float vv = acc[mt][nt][r] + bcol;
          if (RELU) vv = vv > 0.f ? vv : 0.f;
          if (OUTF32) ((float*)Out)[(size_t)row * Nc + col] = vv;
          else        ((bf16_t*)Out)[(size_t)row * Nc + col] = (bf16_t)vv;
        }
      }
    }
}

// ------- MFMA GEMM 128x128, bf16 input, global_load_lds + XOR swizzle -----
template<int K, bool RELU, bool OUTF32>
__global__ __launch_bounds__(256) void gemm128_dma_kernel(
    const bf16_t* __restrict__ U, const bf16_t* __restrict__ Wt,
    const float* __restrict__ bias, void* __restrict__ Out, int M, int Nc) {
  __shared__ bf16_t Ut[128 * 64];
  __shared__ bf16_t Wl[128 * 64];
  const int t = threadIdx.x;
  const int lane = t & 63;
  const int wave = t >> 6;
  const int m0 = blockIdx.x * 128;
  const int n0 = blockIdx.y * 128;
  const int wm = (wave >> 1) * 64;
  const int wn = (wave & 1) * 64;
  const int lr = lane & 15;
  const int lq = lane >> 4;
  const int subrow = wave * 8 + (lane >> 3);        // + q*32
  const int lchunk = (lane & 7) ^ (lane >> 3);      // logical chunk to fetch
  f32x4 acc[4][4] = {};

  for (int k0 = 0; k0 < K; k0 += 64) {
#pragma unroll
    for (int q = 0; q < 4; ++q) {
      const int row = q * 32 + subrow;
      int urow = m0 + row; if (urow >= M) urow = M - 1;
      dma16(U + (size_t)urow * K + k0 + lchunk * 8, &Ut[(q * 32 + wave * 8) * 64]);
      dma16(Wt + (size_t)(n0 + row) * K + k0 + lchunk * 8, &Wl[(q * 32 + wave * 8) * 64]);
    }
    __syncthreads();
#pragma unroll
    for (int s = 0; s < 2; ++s) {
      bf16x8 a[4], b[4];
#pragma unroll
      for (int mt = 0; mt < 4; ++mt)
        a[mt] = *(const bf16x8*)(&Ut[(wm + mt * 16 + lr) * 64 + (((s * 4 + lq) ^ (lr & 7)) << 3)]);
#pragma unroll
      for (int nt = 0; nt < 4; ++nt)
        b[nt] = *(const bf16x8*)(&Wl[(wn + nt * 16 + lr) * 64 + (((s * 4 + lq) ^ (lr & 7)) << 3)]);
#pragma unroll
      for (int mt = 0; mt < 4; ++mt)
#pragma unroll
        for (int nt = 0; nt < 4; ++nt)
          acc[mt][nt] = __builtin_amdgcn_mfma_f32_16x16x32_bf16(
              a[mt], b[nt], acc[mt][nt], 0, 0, 0);
    }
    __syncthreads();
  }

#pragma unroll
  for (int mt = 0; mt < 4; ++mt)
#pragma unroll
    for (int nt = 0; nt < 4; ++nt) {
      int col = n0 + wn + nt * 16 + lr;
      float bcol = bias[col];
#pragma unroll
      for (int r = 0; r < 4; ++r) {
        int row = m0 + wm + mt * 16 + lq * 4 + r;
        if (row < M) {
          float vv = acc[mt][nt][r] + bcol;
          if (RELU) vv = vv > 0.f ? vv : 0.f;
          if (OUTF32) ((float*)Out)[(size_t)row * Nc + col] = vv;
          else        ((bf16_t*)Out)[(size_t)row * Nc + col] = (bf16_t)vv;
        }
      }
    }
}

// ---------------- fused GINE gather with MFMA edge-linear (v4) -----------
__global__ __launch_bounds__(256) void gine_gather_mfma_kernel(
    const bf16_t* __restrict__ h, const bf16_t* __restrict__ eat16,
    const int* __restrict__ src_sorted, const int* __restrict__ offs,
    const bf16_t* __restrict__ ewt, const float* __restrict__ eb,
    const float* __restrict__ eps_p, bf16_t* __restrict__ u) {
  constexpr int HP = H + 8;
  __shared__ bf16_t slin[2][16 * HP];  // 16.9 KB
  const int t = threadIdx.x;
  const int wave = t >> 6;
  const int lane = t & 63;
  const int lr = lane & 15;
  const int lq = lane >> 4;
  const int lane4 = lane * 4;
  const int n0 = blockIdx.x * 4;
  const int nodeN = n0 + wave;

  bf16x4 hs = *(const bf16x4*)(h + (size_t)nodeN * H + lane4);

  bf16x8 bfrag[4];
#pragma unroll
  for (int nt = 0; nt < 4; ++nt) {
    bf16x8 bv = {};
    if (lq < 2)
      bv = *(const bf16x8*)(ewt + ((wave * 64 + nt * 16 + lr) << 4) + (lq << 3));
    bfrag[nt] = bv;
  }
  float ebv[4];
#pragma unroll
  for (int i = 0; i < 4; ++i) ebv[i] = eb[lane4 + i];

  int bs = offs[n0], be = offs[n0 + 4];
  bs = clampi(bs, 0, N_EDGES);
  be = clampi(be, bs, N_EDGES);
  int ns = offs[nodeN], ne = offs[nodeN + 1];
  ns = clampi(ns, bs, be);
  ne = clampi(ne, ns, be);

  float acc[4] = {0.f, 0.f, 0.f, 0.f};
  int parity = 0;

  for (int cb = bs; cb < be; cb += 16, parity ^= 1) {
    int arow = cb + lr;
    if (arow >= N_EDGES) arow = N_EDGES - 1;
    bf16x8 afrag = {};
    if (lq < 2)
      afrag = *(const bf16x8*)(eat16 + ((size_t)arow << 4) + (lq << 3));
    f32x4 c[4];
#pragma unroll
    for (int nt = 0; nt < 4; ++nt) {
      f32x4 z = {};
      c[nt] = __builtin_amdgcn_mfma_f32_16x16x32_bf16(afrag, bfrag[nt], z, 0, 0, 0);
    }
#pragma unroll
    for (int nt = 0; nt < 4; ++nt)
#pragma unroll
      for (int r = 0; r < 4; ++r)
        slin[parity][(lq * 4 + r) * HP + wave * 64 + nt * 16 + lr] = (bf16_t)c[nt][r];
    __syncthreads();
    int j0 = ns > cb ? ns : cb;
    int j1 = ne < cb + 16 ? ne : cb + 16;
    for (int jb = j0; jb < j1; jb += 4) {
      int sidx[4];
#pragma unroll
      for (int q = 0; q < 4; ++q) {
        int jj = jb + q; if (jj > j1 - 1) jj = j1 - 1;
        sidx[q] = src_sorted[jj];
      }
      bf16x4 hv[4];
#pragma unroll
      for (int q = 0; q < 4; ++q)
        hv[q] = *(const bf16x4*)(h + (size_t)sidx[q] * H + lane4);
#pragma unroll
      for (int q = 0; q < 4; ++q) {
        if (jb + q < j1) {
          bf16x4 lv = *(const bf16x4*)(&slin[parity][(jb + q - cb) * HP + lane4]);
#pragma unroll
          for (int i = 0; i < 4; ++i)
            acc[i] += fmaxf((float)hv[q][i] + (float)lv[i] + ebv[i], 0.f);
        }
      }
    }
  }

  const float sc = 1.0f + eps_p[0];
  union { bf16x4 v; uint2 b; } o;
#pragma unroll
  for (int i = 0; i < 4; ++i) o.v[i] = (bf16_t)(sc * (float)hs[i] + acc[i]);
  *(uint2*)(u + (size_t)nodeN * H + lane4) = o.b;
}

// --- GraphNorm (+relu, + optional fused mean-pool), 1 wave/graph, ILP-4 ---
__global__ __launch_bounds__(64) void graphnorm_kernel(
    const bf16_t* __restrict__ v, bf16_t* __restrict__ hout,
    const int* __restrict__ starts,
    const float* __restrict__ w, const float* __restrict__ b,
    const float* __restrict__ ms, float* __restrict__ hg) {
  const int g = blockIdx.x;
  const int c0 = threadIdx.x * 4;
  int s = starts[g], e = starts[g + 1];
  s = clampi(s, 0, N_NODES);
  e = clampi(e, s, N_NODES);
  const float cnt = (float)((e - s) > 1 ? (e - s) : 1);
  float sx[4] = {0.f, 0.f, 0.f, 0.f}, sxx[4] = {0.f, 0.f, 0.f, 0.f};
  int i = s;
  for (; i + 4 <= e; i += 4) {
    bf16x4 xv[4];
#pragma unroll
    for (int q = 0; q < 4; ++q)
      xv[q] = *(const bf16x4*)(v + (size_t)(i + q) * H + c0);
#pragma unroll
    for (int q = 0; q < 4; ++q)
#pragma unroll
      for (int j = 0; j < 4; ++j) { float f = (float)xv[q][j]; sx[j] += f; sxx[j] += f * f; }
  }
  for (; i < e; ++i) {
    bf16x4 xv = *(const bf16x4*)(v + (size_t)i * H + c0);
#pragma unroll
    for (int j = 0; j < 4; ++j) { float f = (float)xv[j]; sx[j] += f; sxx[j] += f * f; }
  }
  float sub[4], inv[4], bb[4], psum[4] = {0.f, 0.f, 0.f, 0.f};
#pragma unroll
  for (int j = 0; j < 4; ++j) {
    float mean = sx[j] / cnt;
    sub[j] = ms[c0 + j] * mean;
    float var = sxx[j] / cnt - 2.f * sub[j] * mean + sub[j] * sub[j];
    var = fmaxf(var, 0.f);
    inv[j] = rsqrtf(var + 1e-5f) * w[c0 + j];
    bb[j] = b[c0 + j];
  }
  i = s;
  for (; i + 4 <= e; i += 4) {
    bf16x4 xv[4];
#pragma unroll
    for (int q = 0; q < 4; ++q)
      xv[q] = *(const bf16x4*)(v + (size_t)(i + q) * H + c0);
#pragma unroll
    for (int q = 0; q < 4; ++q) {
      union { bf16x4 o; uint2 u; } pk;
#pragma unroll
      for (int j = 0; j < 4; ++j) {
        float o = ((float)xv[q][j] - sub[j]) * inv[j] + bb[j];
        o = o > 0.f ? o : 0.f;
        psum[j] += o;
        pk.o[j] = (bf16_t)o;
      }
      *(uint2*)(hout + (size_t)(i + q) * H + c0) = pk.u;
    }
  }
  for (; i < e; ++i) {
    bf16x4 xv = *(const bf16x4*)(v + (size_t)i * H + c0);
    union { bf16x4 o; uint2 u; } pk;
#pragma unroll
    for (int j = 0; j < 4; ++j) {
      float o = ((float)xv[j] - sub[j]) * inv[j] + bb[j];
      o = o > 0.f ? o : 0.f;
      psum[j] += o;
      pk.o[j] = (bf16_t)o;
    }
    *(uint2*)(hout + (size_t)i * H + c0) = pk.u;
  }
  if (hg) {
#pragma unroll
    for (int j = 0; j < 4; ++j) hg[(size_t)g * H + c0 + j] = psum[j] / cnt;
  }
}

// ---- tiny tail heads (Nc=1 / Nc=8): Out[M x Nc] = In(bf16) @ W + b -------
__global__ void head_out_kernel(const bf16_t* __restrict__ In, const float* __restrict__ W,
                                const float* __restrict__ bias, float* __restrict__ Out,
                                int M, int K, int Nc) {
  int idx = blockIdx.x * blockDim.x + threadIdx.x;
  if (idx >= M * Nc) return;
  int r = idx / Nc, n = idx - r * Nc;
  float acc = bias[n];
  const bf16_t* in = In + (size_t)r * K;
  for (int k = 0; k < K; ++k) acc += (float)in[k] * W[(size_t)k * Nc + n];
  Out[idx] = acc;
}

extern "C" void kernel_launch(void* const* d_in, const int* in_sizes, int n_in,
                              void* d_out, int out_size, void* d_ws, size_t ws_size,
                              hipStream_t stream) {
  (void)in_sizes; (void)n_in; (void)out_size; (void)ws_size;
  const float* x        = (const float*)d_in[0];
  const int*   eidx     = (const int*)d_in[1];
  const float* eattr    = (const float*)d_in[2];
  const int*   batch    = (const int*)d_in[3];
  const float* node_W   = (const float*)d_in[4];
  const float* node_b   = (const float*)d_in[5];
  const float* conv_eps = (const float*)d_in[6];
  const float* edge_W   = (const float*)d_in[7];
  const float* edge_b   = (const float*)d_in[8];
  const float* mlp_W1   = (const float*)d_in[9];
  const float* mlp_b1   = (const float*)d_in[10];
  const float* mlp_W2   = (const float*)d_in[11];
  const float* mlp_b2   = (const float*)d_in[12];
  const float* gn_w     = (const float*)d_in[13];
  const float* gn_b     = (const float*)d_in[14];
  const float* gn_ms    = (const float*)d_in[15];
  const float* finv_W1  = (const float*)d_in[16];
  const float* finv_b1  = (const float*)d_in[17];
  const float* finv_W2  = (const float*)d_in[18];
  const float* finv_b2  = (const float*)d_in[19];
  const float* fspu_W1  = (const float*)d_in[20];
  const float* fspu_b1  = (const float*)d_in[21];
  const float* fspu_W2  = (const float*)d_in[22];
  const float* fspu_b2  = (const float*)d_in[23];
  const float* pred_W1  = (const float*)d_in[24];
  const float* pred_b1  = (const float*)d_in[25];
  const float* pred_W2  = (const float*)d_in[26];
  const float* pred_b2  = (const float*)d_in[27];
  const float* adv_W1   = (const float*)d_in[28];
  const float* adv_b1   = (const float*)d_in[29];
  const float* adv_W2   = (const float*)d_in[30];
  const float* adv_b2   = (const float*)d_in[31];
  float* out = (float*)d_out;

  float* out_hg = out;                                  // [G,H]
  float* out_zi = out + (size_t)N_GRAPH * H;            // [G,ZI]
  float* out_zs = out_zi + (size_t)N_GRAPH * ZIC;       // [G,ZS]
  float* out_yh = out_zs + (size_t)N_GRAPH * ZIC;       // [G]
  float* out_ev = out_yh + N_GRAPH;                     // [G,NE]

  // workspace carve-up (~118 MiB total)
  char* wp = (char*)d_ws;
  auto alloc = [&](size_t bytes) { char* p = wp; wp += (bytes + 255) & ~(size_t)255; return p; };
  bf16_t* A        = (bf16_t*)alloc((size_t)N_NODES * H * 2);   // h / t
  bf16_t* B        = (bf16_t*)alloc((size_t)N_NODES * H * 2);   // u / v
  bf16_t* Wt       = (bf16_t*)alloc((size_t)(H * ND + 6 * H * H) * 2);
  bf16_t* WtH      = (bf16_t*)alloc((size_t)(2 * ZIC * H + 4 * ZIC * ZIC) * 2);
  bf16_t* ewt16    = (bf16_t*)alloc((size_t)3 * 256 * 16 * 2);
  bf16_t* eat16    = (bf16_t*)alloc((size_t)N_EDGES * 16 * 2);
  int*    starts   = (int*)alloc((size_t)(N_GRAPH + 1) * 4);
  int*    counts   = (int*)alloc((size_t)N_NODES * 4);
  int*    cursor   = (int*)alloc((size_t)N_NODES * 4);
  int*    offs     = (int*)alloc((size_t)(N_NODES + 1) * 4);
  int*    bsum     = (int*)alloc((size_t)SCAN_B * 4);
  int*    src_srt  = (int*)alloc((size_t)N_EDGES * 4);
  bf16_t* tmp1     = (bf16_t*)alloc((size_t)N_GRAPH * ZIC * 2);
  bf16_t* tmp2     = (bf16_t*)alloc((size_t)N_GRAPH * ZIC * 2);

  const int* srcp = eidx;
  const int* dstp = eidx + N_EDGES;
  const int nscan = (N_NODES + SCAN_B - 1) / SCAN_B;

  compute_starts_kernel<<<(N_NODES + 255) / 256, 256, 0, stream>>>(batch, starts, N_NODES, N_GRAPH);

  zero2_kernel<<<(N_NODES + 255) / 256, 256, 0, stream>>>(counts, cursor, N_NODES);
  count_deg_kernel<<<(N_EDGES + 255) / 256, 256, 0, stream>>>(dstp, counts, N_EDGES, N_NODES);
  scan1_kernel<<<nscan, SCAN_B, 0, stream>>>(counts, offs, bsum, N_NODES);
  scan2_kernel<<<1, 64, 0, stream>>>(bsum, nscan);
  scan3_kernel<<<nscan, SCAN_B, 0, stream>>>(offs, bsum, N_NODES);
  fill_scatter_kernel<<<(N_EDGES + 255) / 256, 256, 0, stream>>>(
      srcp, dstp, eattr, offs, cursor, src_srt, eat16, N_EDGES, N_NODES);
  build_ewt16_kernel<<<(3 * 256 * 16 + 255) / 256, 256, 0, stream>>>(edge_W, ewt16);

  bf16_t* WtN = Wt;
  bf16_t* Wt1base = Wt + H * ND;                      // l-th at stride 2*H*H
  bf16_t* Wt2base = Wt + H * ND + (size_t)H * H;      // l-th at stride 2*H*H
  auto Wt1l = [&](int l) { return Wt1base + (size_t)(2 * l) * H * H; };
  auto Wt2l = [&](int l) { return Wt2base + (size_t)(2 * l) * H * H; };
  transpose_kernel<<<dim3(H / 32, ND / 32, 1), dim3(32, 8), 0, stream>>>(node_W, WtN, ND, H, 0, 0);
  transpose_kernel<<<dim3(H / 32, H / 32, 3), dim3(32, 8), 0, stream>>>(
      mlp_W1, Wt1base, H, H, (size_t)H * H, (size_t)2 * H * H);
  transpose_kernel<<<dim3(H / 32, H / 32, 3), dim3(32, 8), 0, stream>>>(
      mlp_W2, Wt2base, H, H, (size_t)H * H, (size_t)2 * H * H);

  bf16_t* fT1 = WtH;                          // [128 x 256]
  bf16_t* fT2 = fT1 + ZIC * H;                // [128 x 128]
  bf16_t* sT1 = fT2 + ZIC * ZIC;              // [128 x 256]
  bf16_t* sT2 = sT1 + ZIC * H;                // [128 x 128]
  bf16_t* pT1 = sT2 + ZIC * ZIC;              // [128 x 128]
  bf16_t* aT1 = pT1 + ZIC * ZIC;              // [128 x 128]
  transpose_kernel<<<dim3(ZIC / 32, H / 32, 1), dim3(32, 8), 0, stream>>>(finv_W1, fT1, H, ZIC, 0, 0);
  transpose_kernel<<<dim3(ZIC / 32, ZIC / 32, 1), dim3(32, 8), 0, stream>>>(finv_W2, fT2, ZIC, ZIC, 0, 0);
  transpose_kernel<<<dim3(ZIC / 32, H / 32, 1), dim3(32, 8), 0, stream>>>(fspu_W1, sT1, H, ZIC, 0, 0);
  transpose_kernel<<<dim3(ZIC / 32, ZIC / 32, 1), dim3(32, 8), 0, stream>>>(fspu_W2, sT2, ZIC, ZIC, 0, 0);
  transpose_kernel<<<dim3(ZIC / 32, ZIC / 32, 1), dim3(32, 8), 0, stream>>>(pred_W1, pT1, ZIC, ZIC, 0, 0);
  transpose_kernel<<<dim3(ZIC / 32, ZIC / 32, 1), dim3(32, 8), 0, stream>>>(adv_W1, aT1, ZIC, ZIC, 0, 0);

  dim3 ggrid((N_NODES + 127) / 128, H / 128);
  // h = x @ node_W + node_b (fp32 input -> VGPR-staging kernel)
  gemm128_kernel<ND, false, false><<<ggrid, 256, 0, stream>>>(x, WtN, node_b, A, N_NODES, H);

  for (int l = 0; l < 3; ++l) {
    gine_gather_mfma_kernel<<<N_NODES / 4, 256, 0, stream>>>(
        A, eat16, src_srt, offs, ewt16 + (size_t)l * 256 * 16,
        edge_b + l * H, conv_eps + l, B);
    gemm128_dma_kernel<H, true,  false><<<ggrid, 256, 0, stream>>>(B, Wt1l(l), mlp_b1 + l * H, A, N_NODES, H);
    gemm128_dma_kernel<H, false, false><<<ggrid, 256, 0, stream>>>(A, Wt2l(l), mlp_b2 + l * H, B, N_NODES, H);
    graphnorm_kernel<<<N_GRAPH, 64, 0, stream>>>(B, A, starts, gn_w + l * H, gn_b + l * H,
                                                 gn_ms + l * H, (l == 2) ? out_hg : nullptr);
  }

  // heads via 64x64-tile GEMM (M=4096 -> 128 blocks: better CU coverage)
  dim3 hgrid(N_GRAPH / 64, ZIC / 64);
  gemm64_kernel<H,   true,  false, float ><<<hgrid, 256, 0, stream>>>(out_hg, fT1, finv_b1, tmp1, N_GRAPH, ZIC);
  gemm64_kernel<ZIC, false, true,  bf16_t><<<hgrid, 256, 0, stream>>>(tmp1, fT2, finv_b2, out_zi, N_GRAPH, ZIC);
  gemm64_kernel<H,   true,  false, float ><<<hgrid, 256, 0, stream>>>(out_hg, sT1, fspu_b1, tmp2, N_GRAPH, ZIC);
  gemm64_kernel<ZIC, false, true,  bf16_t><<<hgrid, 256, 0, stream>>>(tmp2, sT2, fspu_b2, out_zs, N_GRAPH, ZIC);
  gemm64_kernel<ZIC, true,  false, float ><<<hgrid, 256, 0, stream>>>(out_zi, pT1, pred_b1, tmp1, N_GRAPH, ZIC);
  gemm64_kernel<ZIC, true,  false, float ><<<hgrid, 256, 0, stream>>>(out_zi, aT1, adv_b1, tmp2, N_GRAPH, ZIC);
  head_out_kernel<<<(N_GRAPH + 255) / 256, 256, 0, stream>>>(tmp1, pred_W2, pred_b2, out_yh, N_GRAPH, ZIC, 1);
  head_out_kernel<<<(N_GRAPH * NE + 255) / 256, 256, 0, stream>>>(tmp2, adv_W2, adv_b2, out_ev, N_GRAPH, ZIC, NE);
}